// Round 6
// baseline (2136.139 us; speedup 1.0000x reference)
//
#include <hip/hip_runtime.h>
#include <hip/hip_bf16.h>
#include <math.h>

#define B_       2
#define L_       4096
#define DIM_     1024
#define DINNER_  2048
#define DSTATE_  64
#define NH_      32
#define HD_      64
#define CONVDIM_ 2176
#define DIP_     4256
#define M_       (B_*L_)   // 8192
#define XRW_     2208      // xr row width: xBC raw (2176) + dt_raw (32)

typedef __attribute__((ext_vector_type(8))) short short8;
typedef __attribute__((ext_vector_type(4))) float floatx4;
typedef __hip_bfloat16 bf16;

__device__ __forceinline__ float bf2f(unsigned short u) {
    unsigned int v = ((unsigned int)u) << 16;
    return __builtin_bit_cast(float, v);
}
__device__ __forceinline__ unsigned short f2bf(float f) {
    unsigned int x = __builtin_bit_cast(unsigned int, f);
    unsigned int lsb = (x >> 16) & 1u;
    x += 0x7fffu + lsb;
    return (unsigned short)(x >> 16);
}

// Stage 8 source elements as 8 bf16 (16 B) into LDS.
__device__ __forceinline__ void stage8(const float* __restrict__ src, short* dst) {
    uint4 a = *reinterpret_cast<const uint4*>(src);
    uint4 b = *reinterpret_cast<const uint4*>(src + 4);
    unsigned int w0 = (unsigned int)f2bf(__builtin_bit_cast(float, a.x)) |
                      ((unsigned int)f2bf(__builtin_bit_cast(float, a.y)) << 16);
    unsigned int w1 = (unsigned int)f2bf(__builtin_bit_cast(float, a.z)) |
                      ((unsigned int)f2bf(__builtin_bit_cast(float, a.w)) << 16);
    unsigned int w2 = (unsigned int)f2bf(__builtin_bit_cast(float, b.x)) |
                      ((unsigned int)f2bf(__builtin_bit_cast(float, b.y)) << 16);
    unsigned int w3 = (unsigned int)f2bf(__builtin_bit_cast(float, b.z)) |
                      ((unsigned int)f2bf(__builtin_bit_cast(float, b.w)) << 16);
    *reinterpret_cast<uint4*>(dst) = make_uint4(w0, w1, w2, w3);
}
__device__ __forceinline__ void stage8(const bf16* __restrict__ src, short* dst) {
    *reinterpret_cast<uint4*>(dst) = *reinterpret_cast<const uint4*>(src);
}

// Typed output store: bf16 or f32.
__device__ __forceinline__ void storeo(bf16* p, float v) {
    *reinterpret_cast<unsigned short*>(p) = f2bf(v);
}
__device__ __forceinline__ void storeo(float* p, float v) { *p = v; }

// ---------------------------------------------------------------------------
// GEMM: C[m,n] = sum_k A[m,k] * W[n,k]; A: MxK (TA), W: NxK (TW), out TO.
// 128x128 tile, 4 waves 2x2, mfma 16x16x32 bf16, BK=64, LDS pad (stride 72).
// Epilogue split: n < split -> outA[m*strideA+n]; else outB[m*strideB+n-split]
// ---------------------------------------------------------------------------
template <typename TA, typename TW, typename TO>
__global__ __launch_bounds__(256) void gemm_bt(
    const TA* __restrict__ A, const TW* __restrict__ W,
    TO* __restrict__ outA, TO* __restrict__ outB,
    int M, int N, int K, int split, int strideA, int strideB)
{
    __shared__ short As[128*72];
    __shared__ short Ws[128*72];
    const int tid  = threadIdx.x;
    const int m0   = blockIdx.y * 128;
    const int n0   = blockIdx.x * 128;
    const int wave = tid >> 6;
    const int lane = tid & 63;
    const int wm   = (wave >> 1) * 64;
    const int wn   = (wave & 1) * 64;
    const int ln   = lane & 15;
    const int quad = lane >> 4;

    floatx4 acc[4][4];
#pragma unroll
    for (int i = 0; i < 4; i++)
#pragma unroll
        for (int j = 0; j < 4; j++) acc[i][j] = (floatx4){0.f, 0.f, 0.f, 0.f};

    for (int k0 = 0; k0 < K; k0 += 64) {
#pragma unroll
        for (int it = 0; it < 4; it++) {
            int idx = tid + it * 256;          // 0..1023
            int row = idx >> 3;
            int c8  = (idx & 7) * 8;
            stage8(A + (size_t)(m0 + row) * K + k0 + c8, &As[row * 72 + c8]);
            if (n0 + row < N)
                stage8(W + (size_t)(n0 + row) * K + k0 + c8, &Ws[row * 72 + c8]);
            else
                *reinterpret_cast<uint4*>(&Ws[row * 72 + c8]) = make_uint4(0u, 0u, 0u, 0u);
        }
        __syncthreads();
#pragma unroll
        for (int kk = 0; kk < 64; kk += 32) {
            short8 af[4], bfv[4];
#pragma unroll
            for (int i = 0; i < 4; i++)
                af[i] = *reinterpret_cast<const short8*>(&As[(wm + i * 16 + ln) * 72 + kk + quad * 8]);
#pragma unroll
            for (int j = 0; j < 4; j++)
                bfv[j] = *reinterpret_cast<const short8*>(&Ws[(wn + j * 16 + ln) * 72 + kk + quad * 8]);
#pragma unroll
            for (int i = 0; i < 4; i++)
#pragma unroll
                for (int j = 0; j < 4; j++)
                    acc[i][j] = __builtin_amdgcn_mfma_f32_16x16x32_bf16(af[i], bfv[j], acc[i][j], 0, 0, 0);
        }
        __syncthreads();
    }

#pragma unroll
    for (int i = 0; i < 4; i++) {
#pragma unroll
        for (int j = 0; j < 4; j++) {
#pragma unroll
            for (int r = 0; r < 4; r++) {
                int grow = m0 + wm + i * 16 + quad * 4 + r;
                int gcol = n0 + wn + j * 16 + ln;
                if (gcol < N) {
                    if (gcol < split)
                        storeo(outA + (size_t)grow * strideA + gcol, acc[i][j][r]);
                    else
                        storeo(outB + (size_t)grow * strideB + (gcol - split), acc[i][j][r]);
                }
            }
        }
    }
}

// ---------------------------------------------------------------------------
// Fused SSM scan: depthwise causal conv(k=4)+bias+silu, softplus(dt), and the
// sequential recurrence. Grid 256 = (b:2, h:32, pb:4). Thread = (pl:16, nb:16)
// owns state h[pl, nb*4..nb*4+3]. y includes +D*x.
// xr row: [0,2048) x-raw, [2048,2112) B-raw, [2112,2176) C-raw, [2176,2208) dt.
// ---------------------------------------------------------------------------
__global__ __launch_bounds__(256) void scan_fused_k(
    const bf16* __restrict__ xr,
    const float* __restrict__ cw, const float* __restrict__ cb,
    const float* __restrict__ dtb, const float* __restrict__ A_log,
    const float* __restrict__ Dp, bf16* __restrict__ y)
{
    __shared__ unsigned short rawB[67*64];
    __shared__ unsigned short rawC[67*64];
    __shared__ unsigned short rawX[67*16];
    __shared__ unsigned short Bs[64*64];
    __shared__ unsigned short Cs[64*64];
    __shared__ unsigned short xs[64*16];
    __shared__ float dts[64];
    __shared__ float ys[64*16];
    __shared__ float wB[64*4], wC[64*4], wX[16*4];
    __shared__ float bB[64], bC[64], bX[16];

    const int tid  = threadIdx.x;
    const int b    = blockIdx.x >> 7;
    const int rem  = blockIdx.x & 127;
    const int h    = rem >> 2;
    const int pb   = rem & 3;
    const int pl   = tid >> 4;
    const int nb   = tid & 15;
    const int xch0 = h * HD_ + pb * 16;

    { int n = tid >> 2, j = tid & 3;
      wB[tid] = cw[(2048 + n) * 4 + j];
      wC[tid] = cw[(2112 + n) * 4 + j]; }
    if (tid < 64) { int jj = tid >> 2, j = tid & 3;
        wX[tid] = cw[(xch0 + jj) * 4 + j];
        bB[tid] = cb[2048 + tid];
        bC[tid] = cb[2112 + tid]; }
    if (tid < 16) bX[tid] = cb[xch0 + tid];

    const float Ah   = -__expf(A_log[h]);
    const float Dh   = Dp[h];
    const float dtbh = dtb[h];
    const unsigned short* xru = (const unsigned short*)xr;

    float hs0 = 0.f, hs1 = 0.f, hs2 = 0.f, hs3 = 0.f;

    for (int t0 = 0; t0 < L_; t0 += 64) {
        for (int q = tid; q < 536; q += 256) {
            int r = q >> 3, c8 = (q & 7) * 8;
            int t = t0 - 3 + r;
            uint4 vB = make_uint4(0u,0u,0u,0u), vC = vB;
            if (t >= 0) {
                size_t ro = (size_t)(b * L_ + t) * XRW_;
                vB = *reinterpret_cast<const uint4*>(xru + ro + 2048 + c8);
                vC = *reinterpret_cast<const uint4*>(xru + ro + 2112 + c8);
            }
            *reinterpret_cast<uint4*>(&rawB[r*64 + c8]) = vB;
            *reinterpret_cast<uint4*>(&rawC[r*64 + c8]) = vC;
        }
        for (int q = tid; q < 134; q += 256) {
            int r = q >> 1, c8 = (q & 1) * 8;
            int t = t0 - 3 + r;
            uint4 vX = make_uint4(0u,0u,0u,0u);
            if (t >= 0)
                vX = *reinterpret_cast<const uint4*>(xru + (size_t)(b * L_ + t) * XRW_ + xch0 + c8);
            *reinterpret_cast<uint4*>(&rawX[r*16 + c8]) = vX;
        }
        if (tid < 64) {
            float v = bf2f(xru[(size_t)(b * L_ + t0 + tid) * XRW_ + 2176 + h]) + dtbh;
            dts[tid] = fmaxf(v, 0.f) + log1pf(__expf(-fabsf(v)));
        }
        __syncthreads();

        for (int q = tid; q < 9216; q += 256) {
            float acc; unsigned short* dst;
            if (q < 4096) {
                int i = q >> 6, c = q & 63; acc = bB[c];
#pragma unroll
                for (int j = 0; j < 4; j++) acc = fmaf(bf2f(rawB[(i+j)*64 + c]), wB[c*4+j], acc);
                dst = &Bs[i*64 + c];
            } else if (q < 8192) {
                int qq = q - 4096; int i = qq >> 6, c = qq & 63; acc = bC[c];
#pragma unroll
                for (int j = 0; j < 4; j++) acc = fmaf(bf2f(rawC[(i+j)*64 + c]), wC[c*4+j], acc);
                dst = &Cs[i*64 + c];
            } else {
                int qq = q - 8192; int i = qq >> 4, c = qq & 15; acc = bX[c];
#pragma unroll
                for (int j = 0; j < 4; j++) acc = fmaf(bf2f(rawX[(i+j)*16 + c]), wX[c*4+j], acc);
                dst = &xs[i*16 + c];
            }
            *dst = f2bf(acc / (1.f + __expf(-acc)));
        }
        __syncthreads();

        for (int i = 0; i < 64; i++) {
            float dtv  = dts[i];
            float dA   = __expf(dtv * Ah);
            float xv   = bf2f(xs[i*16 + pl]);
            float coef = dtv * xv;
            uint2 bv = *reinterpret_cast<const uint2*>(&Bs[i*64 + nb*4]);
            uint2 cv = *reinterpret_cast<const uint2*>(&Cs[i*64 + nb*4]);
            float b0 = bf2f((unsigned short)(bv.x & 0xffffu)), b1 = bf2f((unsigned short)(bv.x >> 16));
            float b2 = bf2f((unsigned short)(bv.y & 0xffffu)), b3 = bf2f((unsigned short)(bv.y >> 16));
            float c0 = bf2f((unsigned short)(cv.x & 0xffffu)), c1 = bf2f((unsigned short)(cv.x >> 16));
            float c2 = bf2f((unsigned short)(cv.y & 0xffffu)), c3 = bf2f((unsigned short)(cv.y >> 16));
            hs0 = fmaf(hs0, dA, coef * b0);
            hs1 = fmaf(hs1, dA, coef * b1);
            hs2 = fmaf(hs2, dA, coef * b2);
            hs3 = fmaf(hs3, dA, coef * b3);
            float ysum = hs0 * c0 + hs1 * c1 + hs2 * c2 + hs3 * c3;
            ysum += __shfl_xor(ysum, 1);
            ysum += __shfl_xor(ysum, 2);
            ysum += __shfl_xor(ysum, 4);
            ysum += __shfl_xor(ysum, 8);
            if (nb == 0) ys[i*16 + pl] = fmaf(Dh, xv, ysum);
        }
        __syncthreads();
#pragma unroll
        for (int it2 = 0; it2 < 4; it2++) {
            int idx = tid + it2 * 256;             // 0..1023
            int i = idx >> 4, p = idx & 15;
            ((unsigned short*)y)[(size_t)(b * L_ + t0 + i) * DINNER_ + xch0 + p] = f2bf(ys[i*16 + p]);
        }
        __syncthreads();
    }
}

// ---------------------------------------------------------------------------
// y = (y * silu(z)); y *= rsqrt(mean(y^2)+eps) * norm_w   (in place, bf16)
// ---------------------------------------------------------------------------
__global__ __launch_bounds__(256) void gate_norm_k(
    bf16* __restrict__ y, const bf16* __restrict__ zbuf, const float* __restrict__ nw)
{
    __shared__ float red[4];
    int row = blockIdx.x;
    int tid = threadIdx.x;
    unsigned short* yy = (unsigned short*)y;
    const unsigned short* zz = (const unsigned short*)zbuf;

    uint4 yv = *reinterpret_cast<uint4*>(&yy[(size_t)row * DINNER_ + tid * 8]);
    uint4 zv = *reinterpret_cast<const uint4*>(&zz[(size_t)row * DINNER_ + tid * 8]);
    unsigned int yw[4] = {yv.x, yv.y, yv.z, yv.w};
    unsigned int zw[4] = {zv.x, zv.y, zv.z, zv.w};
    float g[8];
    float ss = 0.f;
#pragma unroll
    for (int q = 0; q < 4; q++) {
        float y0 = bf2f((unsigned short)(yw[q] & 0xffffu)), y1 = bf2f((unsigned short)(yw[q] >> 16));
        float z0 = bf2f((unsigned short)(zw[q] & 0xffffu)), z1 = bf2f((unsigned short)(zw[q] >> 16));
        float g0 = y0 * (z0 / (1.f + __expf(-z0)));
        float g1 = y1 * (z1 / (1.f + __expf(-z1)));
        g[q * 2] = g0; g[q * 2 + 1] = g1;
        ss += g0 * g0 + g1 * g1;
    }
#pragma unroll
    for (int o = 1; o < 64; o <<= 1) ss += __shfl_xor(ss, o);
    if ((tid & 63) == 0) red[tid >> 6] = ss;
    __syncthreads();
    float tot = red[0] + red[1] + red[2] + red[3];
    float rinv = rsqrtf(tot * (1.f / DINNER_) + 1e-5f);

    unsigned int ow[4];
#pragma unroll
    for (int q = 0; q < 4; q++) {
        float w0 = nw[tid * 8 + q * 2];
        float w1 = nw[tid * 8 + q * 2 + 1];
        unsigned short o0 = f2bf(g[q * 2] * rinv * w0);
        unsigned short o1 = f2bf(g[q * 2 + 1] * rinv * w1);
        ow[q] = (unsigned int)o0 | ((unsigned int)o1 << 16);
    }
    *reinterpret_cast<uint4*>(&yy[(size_t)row * DINNER_ + tid * 8]) =
        make_uint4(ow[0], ow[1], ow[2], ow[3]);
}

// ---------------------------------------------------------------------------

extern "C" void kernel_launch(void* const* d_in, const int* in_sizes, int n_in,
                              void* d_out, int out_size, void* d_ws, size_t ws_size,
                              hipStream_t stream)
{
    const float* X    = (const float*)d_in[0];   // (2,4096,1024) f32
    const float* Wip  = (const float*)d_in[1];   // (4256,1024)   f32
    const float* cw   = (const float*)d_in[2];   // (2176,1,4)    f32
    const float* cb   = (const float*)d_in[3];   // (2176,)       f32
    const float* dtb  = (const float*)d_in[4];   // (32,)         f32
    const float* Alog = (const float*)d_in[5];   // (32,)         f32
    const float* Dp   = (const float*)d_in[6];   // (32,)         f32
    const float* nw   = (const float*)d_in[7];   // (2048,)       f32
    const float* Wop  = (const float*)d_in[8];   // (1024,2048)   f32
    const float* Wth  = (const float*)d_in[9];   // (2048,1024)   f32
    float* out = (float*)d_out;                  // f32: HK (8.4M) | HV (8.4M)

    // Workspace (69,730,304 B):
    //   zbuf [0, 33554432)        : z, M x 2048 bf16       (gemm1 -> gate)
    //   xr   [33554432, 69730304) : xBC+dt raw, M x 2208 bf16 (gemm1 -> scan)
    //   Hbuf aliases xr           : M x 1024 bf16          (gemm2 -> gemm3)
    //   ybuf = d_out[0, 33.5MB)   : M x 2048 bf16          (scan -> gemm2; dead
    //                               before gemm3 overwrites d_out with f32)
    char* ws = (char*)d_ws;
    bf16* zbuf = (bf16*)(ws);
    bf16* xr   = (bf16*)(ws + 33554432);
    bf16* Hbuf = (bf16*)(ws + 33554432);
    bf16* ybuf = (bf16*)d_out;

    dim3 blk(256);

    // 1) zxbcdt = X @ in_proj^T; split: z -> zbuf (bf16), xBC+dt_raw -> xr (bf16)
    gemm_bt<float, float, bf16><<<dim3((DIP_ + 127) / 128, M_ / 128), blk, 0, stream>>>(
        X, Wip, zbuf, xr, M_, DIP_, DIM_, DINNER_, DINNER_, XRW_);

    // 2) fused conv+silu+softplus+scan -> ybuf (bf16, in d_out's first half)
    scan_fused_k<<<256, blk, 0, stream>>>(xr, cw, cb, dtb, Alog, Dp, ybuf);

    // 3) gate by silu(z) + RMSNorm, in place on ybuf
    gate_norm_k<<<M_, blk, 0, stream>>>(ybuf, zbuf, nw);

    // 4) H = ynorm @ out_proj^T  (N=1024, K=2048) -> Hbuf bf16 (xr dead)
    gemm_bt<bf16, float, bf16><<<dim3(DIM_ / 128, M_ / 128), blk, 0, stream>>>(
        ybuf, Wop, Hbuf, Hbuf, M_, DIM_, DINNER_, DIM_, DIM_, DIM_);

    // 5) HKV = H @ to_h^T (N=2048, K=1024); f32 epilogue split HK | HV
    gemm_bt<bf16, float, float><<<dim3(DINNER_ / 128, M_ / 128), blk, 0, stream>>>(
        Hbuf, Wth, out, out + (size_t)M_ * DIM_, M_, DINNER_, DIM_, DIM_, DIM_, DIM_);
}

// Round 7
// 779.392 us; speedup vs baseline: 2.7408x; 2.7408x over previous
//
#include <hip/hip_runtime.h>
#include <hip/hip_bf16.h>
#include <math.h>

#define B_       2
#define L_       4096
#define DIM_     1024
#define DINNER_  2048
#define DSTATE_  64
#define NH_      32
#define HD_      64
#define CONVDIM_ 2176
#define DIP_     4256
#define M_       (B_*L_)   // 8192
#define XRW_     2208      // xr row width: xBC raw (2176) + dt_raw (32)
#define NC_      64        // chunks (L/64)

typedef __attribute__((ext_vector_type(8))) short short8;
typedef __attribute__((ext_vector_type(4))) float floatx4;
typedef __hip_bfloat16 bf16;

__device__ __forceinline__ float bf2f(unsigned short u) {
    unsigned int v = ((unsigned int)u) << 16;
    return __builtin_bit_cast(float, v);
}
__device__ __forceinline__ unsigned short f2bf(float f) {
    unsigned int x = __builtin_bit_cast(unsigned int, f);
    unsigned int lsb = (x >> 16) & 1u;
    x += 0x7fffu + lsb;
    return (unsigned short)(x >> 16);
}

__device__ __forceinline__ void stage8(const float* __restrict__ src, short* dst) {
    uint4 a = *reinterpret_cast<const uint4*>(src);
    uint4 b = *reinterpret_cast<const uint4*>(src + 4);
    unsigned int w0 = (unsigned int)f2bf(__builtin_bit_cast(float, a.x)) |
                      ((unsigned int)f2bf(__builtin_bit_cast(float, a.y)) << 16);
    unsigned int w1 = (unsigned int)f2bf(__builtin_bit_cast(float, a.z)) |
                      ((unsigned int)f2bf(__builtin_bit_cast(float, a.w)) << 16);
    unsigned int w2 = (unsigned int)f2bf(__builtin_bit_cast(float, b.x)) |
                      ((unsigned int)f2bf(__builtin_bit_cast(float, b.y)) << 16);
    unsigned int w3 = (unsigned int)f2bf(__builtin_bit_cast(float, b.z)) |
                      ((unsigned int)f2bf(__builtin_bit_cast(float, b.w)) << 16);
    *reinterpret_cast<uint4*>(dst) = make_uint4(w0, w1, w2, w3);
}
__device__ __forceinline__ void stage8(const bf16* __restrict__ src, short* dst) {
    *reinterpret_cast<uint4*>(dst) = *reinterpret_cast<const uint4*>(src);
}
__device__ __forceinline__ void storeo(bf16* p, float v) {
    *reinterpret_cast<unsigned short*>(p) = f2bf(v);
}
__device__ __forceinline__ void storeo(float* p, float v) { *p = v; }

// ---------------------------------------------------------------------------
// GEMM: C[m,n] = sum_k A[m,k]*W[n,k]; 128x128 tile, mfma 16x16x32 bf16.
// (unchanged from round 6 — validated)
// ---------------------------------------------------------------------------
template <typename TA, typename TW, typename TO>
__global__ __launch_bounds__(256) void gemm_bt(
    const TA* __restrict__ A, const TW* __restrict__ W,
    TO* __restrict__ outA, TO* __restrict__ outB,
    int M, int N, int K, int split, int strideA, int strideB)
{
    __shared__ short As[128*72];
    __shared__ short Ws[128*72];
    const int tid  = threadIdx.x;
    const int m0   = blockIdx.y * 128;
    const int n0   = blockIdx.x * 128;
    const int wave = tid >> 6;
    const int lane = tid & 63;
    const int wm   = (wave >> 1) * 64;
    const int wn   = (wave & 1) * 64;
    const int ln   = lane & 15;
    const int quad = lane >> 4;

    floatx4 acc[4][4];
#pragma unroll
    for (int i = 0; i < 4; i++)
#pragma unroll
        for (int j = 0; j < 4; j++) acc[i][j] = (floatx4){0.f, 0.f, 0.f, 0.f};

    for (int k0 = 0; k0 < K; k0 += 64) {
#pragma unroll
        for (int it = 0; it < 4; it++) {
            int idx = tid + it * 256;
            int row = idx >> 3;
            int c8  = (idx & 7) * 8;
            stage8(A + (size_t)(m0 + row) * K + k0 + c8, &As[row * 72 + c8]);
            if (n0 + row < N)
                stage8(W + (size_t)(n0 + row) * K + k0 + c8, &Ws[row * 72 + c8]);
            else
                *reinterpret_cast<uint4*>(&Ws[row * 72 + c8]) = make_uint4(0u, 0u, 0u, 0u);
        }
        __syncthreads();
#pragma unroll
        for (int kk = 0; kk < 64; kk += 32) {
            short8 af[4], bfv[4];
#pragma unroll
            for (int i = 0; i < 4; i++)
                af[i] = *reinterpret_cast<const short8*>(&As[(wm + i * 16 + ln) * 72 + kk + quad * 8]);
#pragma unroll
            for (int j = 0; j < 4; j++)
                bfv[j] = *reinterpret_cast<const short8*>(&Ws[(wn + j * 16 + ln) * 72 + kk + quad * 8]);
#pragma unroll
            for (int i = 0; i < 4; i++)
#pragma unroll
                for (int j = 0; j < 4; j++)
                    acc[i][j] = __builtin_amdgcn_mfma_f32_16x16x32_bf16(af[i], bfv[j], acc[i][j], 0, 0, 0);
        }
        __syncthreads();
    }

#pragma unroll
    for (int i = 0; i < 4; i++)
#pragma unroll
        for (int j = 0; j < 4; j++)
#pragma unroll
            for (int r = 0; r < 4; r++) {
                int grow = m0 + wm + i * 16 + quad * 4 + r;
                int gcol = n0 + wn + j * 16 + ln;
                if (gcol < N) {
                    if (gcol < split)
                        storeo(outA + (size_t)grow * strideA + gcol, acc[i][j][r]);
                    else
                        storeo(outB + (size_t)grow * strideB + (gcol - split), acc[i][j][r]);
                }
            }
}

// ---------------------------------------------------------------------------
// Pass A: per (b,chunk,h) block: fused conv+silu+softplus, then 3 MFMA GEMMs:
//   G[t][s]    = C[t]·B[s]                       (64x64, K=64 over n)
//   M[t][s]    = (s<=t) ? e^{cum[t]-cum[s]}·dt[s]·G : 0
//   Yintra[t][p] = sum_s M[t][s]·x[s][p] + D·x[t][p]   -> Yg (bf16)
//   S^T[p][n]  = sum_s e^{cum63-cum[s]}·dt[s]·x[s][p]·B[s][n] -> Sg (f32)
// Also stores: Cconv (h==0 only), wcum[t]=e^{cum[t]}, E=e^{cum63}.
// blockIdx.x = ((b*64+c)*32+h)
// ---------------------------------------------------------------------------
__global__ __launch_bounds__(256) void chunk_intra_k(
    const bf16* __restrict__ xr,
    const float* __restrict__ cw, const float* __restrict__ cb,
    const float* __restrict__ dtb, const float* __restrict__ A_log,
    const float* __restrict__ Dp,
    bf16* __restrict__ Yg, float* __restrict__ Sg, bf16* __restrict__ Cg,
    float* __restrict__ wcumG, float* __restrict__ Eg)
{
    __shared__ short Bst[64*72];
    __shared__ short Cst[64*72];
    __shared__ short xT [64*72];
    __shared__ short BwT[64*72];
    __shared__ unsigned short raw[3*67*64];   // rawX | rawB | rawC ; reused as M
    __shared__ float wXc[256], wBc[256], wCc[256];
    __shared__ float bXc[64], bBc[64], bCc[64];
    __shared__ float dts[64], cums[64], wS[64], wcumS[64];

    const int tid  = threadIdx.x;
    const int bid  = blockIdx.x;
    const int h    = bid & 31;
    const int bc   = bid >> 5;        // b*64+c
    const int c    = bc & 63;
    const int b    = bc >> 6;
    const int xch0 = h * 64;
    const unsigned short* xru = (const unsigned short*)xr;

    const float Ah   = -__expf(A_log[h]);
    const float Dh   = Dp[h];
    const float dtbh = dtb[h];

    // conv weights/biases
    { int n = tid >> 2, j = tid & 3;
      wXc[tid] = cw[(xch0 + n) * 4 + j];
      wBc[tid] = cw[(2048 + n) * 4 + j];
      wCc[tid] = cw[(2112 + n) * 4 + j]; }
    if (tid < 64) { bXc[tid] = cb[xch0 + tid]; bBc[tid] = cb[2048 + tid]; bCc[tid] = cb[2112 + tid]; }

    // raw staging: rows r in [0,67) -> t = c*64-3+r (zeros for t<0)
    for (int q = tid; q < 536; q += 256) {
        int r = q >> 3, c8 = (q & 7) * 8;
        int rt = c * 64 - 3 + r;
        uint4 vX = make_uint4(0u,0u,0u,0u), vB = vX, vC = vX;
        if (rt >= 0) {
            size_t ro = (size_t)(b * L_ + rt) * XRW_;
            vX = *reinterpret_cast<const uint4*>(xru + ro + xch0 + c8);
            vB = *reinterpret_cast<const uint4*>(xru + ro + 2048 + c8);
            vC = *reinterpret_cast<const uint4*>(xru + ro + 2112 + c8);
        }
        *reinterpret_cast<uint4*>(&raw[r*64 + c8])        = vX;
        *reinterpret_cast<uint4*>(&raw[4288 + r*64 + c8]) = vB;
        *reinterpret_cast<uint4*>(&raw[8576 + r*64 + c8]) = vC;
    }
    if (tid < 64) {
        float v = bf2f(xru[(size_t)(b * L_ + c * 64 + tid) * XRW_ + 2176 + h]) + dtbh;
        dts[tid] = fmaxf(v, 0.f) + log1pf(__expf(-fabsf(v)));
    }
    __syncthreads();

    if (tid == 0) {
        float cc = 0.f;
        for (int t = 0; t < 64; t++) { cc += dts[t] * Ah; cums[t] = cc; }
    }
    __syncthreads();
    if (tid < 64) {
        wS[tid]    = __expf(cums[63] - cums[tid]) * dts[tid];
        wcumS[tid] = __expf(cums[tid]);
        wcumG[(size_t)bid * 64 + tid] = wcumS[tid];
    }
    if (tid == 0) Eg[bid] = __expf(cums[63]);
    __syncthreads();

    // conv + bias + silu -> Bst/Cst/xT (+BwT, +Cg)
    for (int q = tid; q < 12288; q += 256) {
        int mtx = q >> 12;
        int qq  = q & 4095;
        int s = qq >> 6, ch = qq & 63;
        if (mtx == 0) {
            float a = bBc[ch];
#pragma unroll
            for (int j = 0; j < 4; j++) a = fmaf(bf2f(raw[4288 + (s+j)*64 + ch]), wBc[ch*4+j], a);
            float sv = a / (1.f + __expf(-a));
            Bst[s*72 + ch] = f2bf(sv);
            BwT[ch*72 + s] = f2bf(sv * wS[s]);
        } else if (mtx == 1) {
            float a = bCc[ch];
#pragma unroll
            for (int j = 0; j < 4; j++) a = fmaf(bf2f(raw[8576 + (s+j)*64 + ch]), wCc[ch*4+j], a);
            float sv = a / (1.f + __expf(-a));
            unsigned short u = f2bf(sv);
            Cst[s*72 + ch] = u;
            if (h == 0) ((unsigned short*)Cg)[(size_t)(b*L_ + c*64 + s)*64 + ch] = u;
        } else {
            float a = bXc[ch];
#pragma unroll
            for (int j = 0; j < 4; j++) a = fmaf(bf2f(raw[(s+j)*64 + ch]), wXc[ch*4+j], a);
            float sv = a / (1.f + __expf(-a));
            xT[ch*72 + s] = f2bf(sv);   // transposed: [p][t]
        }
    }
    __syncthreads();

    const int wave = tid >> 6, lane = tid & 63;
    const int ln = lane & 15, quad = lane >> 4;
    const int wm = (wave >> 1) * 32, wn = (wave & 1) * 32;

    // --- G = Cst · Bst^T (out rows t, cols s) ---
    floatx4 accG[2][2];
#pragma unroll
    for (int i = 0; i < 2; i++)
#pragma unroll
        for (int j = 0; j < 2; j++) accG[i][j] = (floatx4){0.f,0.f,0.f,0.f};
#pragma unroll
    for (int kk = 0; kk < 64; kk += 32) {
        short8 af[2], bfv[2];
#pragma unroll
        for (int i = 0; i < 2; i++)
            af[i] = *reinterpret_cast<const short8*>(&Cst[(wm + i*16 + ln)*72 + kk + quad*8]);
#pragma unroll
        for (int j = 0; j < 2; j++)
            bfv[j] = *reinterpret_cast<const short8*>(&Bst[(wn + j*16 + ln)*72 + kk + quad*8]);
#pragma unroll
        for (int i = 0; i < 2; i++)
#pragma unroll
            for (int j = 0; j < 2; j++)
                accG[i][j] = __builtin_amdgcn_mfma_f32_16x16x32_bf16(af[i], bfv[j], accG[i][j], 0,0,0);
    }
    // mask + scale -> M (aliases raw; raw dead)
    short* Mm = (short*)raw;
#pragma unroll
    for (int i = 0; i < 2; i++)
#pragma unroll
        for (int j = 0; j < 2; j++)
#pragma unroll
            for (int r = 0; r < 4; r++) {
                int t = wm + i*16 + quad*4 + r;
                int s = wn + j*16 + ln;
                float v = (s <= t) ? __expf(cums[t] - cums[s]) * dts[s] * accG[i][j][r] : 0.f;
                Mm[t*72 + s] = (short)f2bf(v);
            }
    __syncthreads();

    // --- Yintra = M · xT^T (out rows t, cols p) + D*x ---
    floatx4 accY[2][2];
#pragma unroll
    for (int i = 0; i < 2; i++)
#pragma unroll
        for (int j = 0; j < 2; j++) accY[i][j] = (floatx4){0.f,0.f,0.f,0.f};
#pragma unroll
    for (int kk = 0; kk < 64; kk += 32) {
        short8 af[2], bfv[2];
#pragma unroll
        for (int i = 0; i < 2; i++)
            af[i] = *reinterpret_cast<const short8*>(&Mm[(wm + i*16 + ln)*72 + kk + quad*8]);
#pragma unroll
        for (int j = 0; j < 2; j++)
            bfv[j] = *reinterpret_cast<const short8*>(&xT[(wn + j*16 + ln)*72 + kk + quad*8]);
#pragma unroll
        for (int i = 0; i < 2; i++)
#pragma unroll
            for (int j = 0; j < 2; j++)
                accY[i][j] = __builtin_amdgcn_mfma_f32_16x16x32_bf16(af[i], bfv[j], accY[i][j], 0,0,0);
    }
    unsigned short* Yu = (unsigned short*)Yg;
#pragma unroll
    for (int i = 0; i < 2; i++)
#pragma unroll
        for (int j = 0; j < 2; j++)
#pragma unroll
            for (int r = 0; r < 4; r++) {
                int t = wm + i*16 + quad*4 + r;
                int p = wn + j*16 + ln;
                float yv = accY[i][j][r] + Dh * bf2f((unsigned short)xT[p*72 + t]);
                Yu[(size_t)(b*L_ + c*64 + t)*DINNER_ + xch0 + p] = f2bf(yv);
            }

    // --- S^T = xT · BwT^T (out rows p, cols n) ---
    floatx4 accS[2][2];
#pragma unroll
    for (int i = 0; i < 2; i++)
#pragma unroll
        for (int j = 0; j < 2; j++) accS[i][j] = (floatx4){0.f,0.f,0.f,0.f};
#pragma unroll
    for (int kk = 0; kk < 64; kk += 32) {
        short8 af[2], bfv[2];
#pragma unroll
        for (int i = 0; i < 2; i++)
            af[i] = *reinterpret_cast<const short8*>(&xT[(wm + i*16 + ln)*72 + kk + quad*8]);
#pragma unroll
        for (int j = 0; j < 2; j++)
            bfv[j] = *reinterpret_cast<const short8*>(&BwT[(wn + j*16 + ln)*72 + kk + quad*8]);
#pragma unroll
        for (int i = 0; i < 2; i++)
#pragma unroll
            for (int j = 0; j < 2; j++)
                accS[i][j] = __builtin_amdgcn_mfma_f32_16x16x32_bf16(af[i], bfv[j], accS[i][j], 0,0,0);
    }
#pragma unroll
    for (int i = 0; i < 2; i++)
#pragma unroll
        for (int j = 0; j < 2; j++)
#pragma unroll
            for (int r = 0; r < 4; r++) {
                int p = wm + i*16 + quad*4 + r;
                int n = wn + j*16 + ln;
                Sg[(size_t)bid * 4096 + p*64 + n] = accS[i][j][r];
            }
}

// ---------------------------------------------------------------------------
// Pass B: prefix over chunks. Sg[bid][p][n] := state at START of chunk c;
// run = run*E_c + S_c. thread owns 4 contiguous state elems of one (b,h).
// ---------------------------------------------------------------------------
__global__ __launch_bounds__(256) void chunk_state_k(
    float* __restrict__ Sg, const float* __restrict__ Eg)
{
    int g  = blockIdx.x * 1024 + threadIdx.x * 4;  // (b*32+h)*4096 + e
    int bh = g >> 12;
    int b  = bh >> 5, h = bh & 31;
    int e  = g & 4095;
    float4 run = make_float4(0.f, 0.f, 0.f, 0.f);
    for (int c = 0; c < NC_; c++) {
        int bid = (b * 64 + c) * 32 + h;
        size_t idx = (size_t)bid * 4096 + e;
        float4 s = *reinterpret_cast<float4*>(&Sg[idx]);
        float  E = Eg[bid];
        *reinterpret_cast<float4*>(&Sg[idx]) = run;
        run.x = run.x * E + s.x;
        run.y = run.y * E + s.y;
        run.z = run.z * E + s.z;
        run.w = run.w * E + s.w;
    }
}

// ---------------------------------------------------------------------------
// Pass C: Y[t][p] += e^{cum[t]} * sum_n C[t][n]*hprev^T[p][n]  (in-place RMW)
// ---------------------------------------------------------------------------
__global__ __launch_bounds__(256) void chunk_inter_k(
    const bf16* __restrict__ Cg, const float* __restrict__ Sg,
    const float* __restrict__ wcumG, bf16* __restrict__ Yg)
{
    __shared__ short Cst[64*72];
    __shared__ short hpT[64*72];
    __shared__ float wcumL[64];

    const int tid = threadIdx.x;
    const int bid = blockIdx.x;
    const int h   = bid & 31;
    const int bc  = bid >> 5;
    const int c   = bc & 63;
    const int b   = bc >> 6;

    for (int q = tid; q < 512; q += 256) {
        int r = q >> 3, c8 = (q & 7) * 8;
        *reinterpret_cast<uint4*>(&Cst[r*72 + c8]) =
            *reinterpret_cast<const uint4*>((const unsigned short*)Cg + (size_t)(b*L_ + c*64 + r)*64 + c8);
    }
    for (int q = tid; q < 1024; q += 256) {
        int p = q >> 4, n4 = (q & 15) * 4;
        float4 v = *reinterpret_cast<const float4*>(&Sg[(size_t)bid * 4096 + p*64 + n4]);
        unsigned int lo = (unsigned int)f2bf(v.x) | ((unsigned int)f2bf(v.y) << 16);
        unsigned int hi = (unsigned int)f2bf(v.z) | ((unsigned int)f2bf(v.w) << 16);
        *reinterpret_cast<uint2*>(&hpT[p*72 + n4]) = make_uint2(lo, hi);
    }
    if (tid < 64) wcumL[tid] = wcumG[(size_t)bid * 64 + tid];
    __syncthreads();

    const int wave = tid >> 6, lane = tid & 63;
    const int ln = lane & 15, quad = lane >> 4;
    const int wm = (wave >> 1) * 32, wn = (wave & 1) * 32;

    floatx4 acc[2][2];
#pragma unroll
    for (int i = 0; i < 2; i++)
#pragma unroll
        for (int j = 0; j < 2; j++) acc[i][j] = (floatx4){0.f,0.f,0.f,0.f};
#pragma unroll
    for (int kk = 0; kk < 64; kk += 32) {
        short8 af[2], bfv[2];
#pragma unroll
        for (int i = 0; i < 2; i++)
            af[i] = *reinterpret_cast<const short8*>(&Cst[(wm + i*16 + ln)*72 + kk + quad*8]);
#pragma unroll
        for (int j = 0; j < 2; j++)
            bfv[j] = *reinterpret_cast<const short8*>(&hpT[(wn + j*16 + ln)*72 + kk + quad*8]);
#pragma unroll
        for (int i = 0; i < 2; i++)
#pragma unroll
            for (int j = 0; j < 2; j++)
                acc[i][j] = __builtin_amdgcn_mfma_f32_16x16x32_bf16(af[i], bfv[j], acc[i][j], 0,0,0);
    }
    unsigned short* Yu = (unsigned short*)Yg;
#pragma unroll
    for (int i = 0; i < 2; i++)
#pragma unroll
        for (int j = 0; j < 2; j++)
#pragma unroll
            for (int r = 0; r < 4; r++) {
                int t = wm + i*16 + quad*4 + r;
                int p = wn + j*16 + ln;
                size_t idx = (size_t)(b*L_ + c*64 + t)*DINNER_ + h*64 + p;
                float yv = bf2f(Yu[idx]) + wcumL[t] * acc[i][j][r];
                Yu[idx] = f2bf(yv);
            }
}

// ---------------------------------------------------------------------------
// gate + RMSNorm (unchanged, validated)
// ---------------------------------------------------------------------------
__global__ __launch_bounds__(256) void gate_norm_k(
    bf16* __restrict__ y, const bf16* __restrict__ zbuf, const float* __restrict__ nw)
{
    __shared__ float red[4];
    int row = blockIdx.x;
    int tid = threadIdx.x;
    unsigned short* yy = (unsigned short*)y;
    const unsigned short* zz = (const unsigned short*)zbuf;

    uint4 yv = *reinterpret_cast<uint4*>(&yy[(size_t)row * DINNER_ + tid * 8]);
    uint4 zv = *reinterpret_cast<const uint4*>(&zz[(size_t)row * DINNER_ + tid * 8]);
    unsigned int yw[4] = {yv.x, yv.y, yv.z, yv.w};
    unsigned int zw[4] = {zv.x, zv.y, zv.z, zv.w};
    float g[8];
    float ss = 0.f;
#pragma unroll
    for (int q = 0; q < 4; q++) {
        float y0 = bf2f((unsigned short)(yw[q] & 0xffffu)), y1 = bf2f((unsigned short)(yw[q] >> 16));
        float z0 = bf2f((unsigned short)(zw[q] & 0xffffu)), z1 = bf2f((unsigned short)(zw[q] >> 16));
        float g0 = y0 * (z0 / (1.f + __expf(-z0)));
        float g1 = y1 * (z1 / (1.f + __expf(-z1)));
        g[q * 2] = g0; g[q * 2 + 1] = g1;
        ss += g0 * g0 + g1 * g1;
    }
#pragma unroll
    for (int o = 1; o < 64; o <<= 1) ss += __shfl_xor(ss, o);
    if ((tid & 63) == 0) red[tid >> 6] = ss;
    __syncthreads();
    float tot = red[0] + red[1] + red[2] + red[3];
    float rinv = rsqrtf(tot * (1.f / DINNER_) + 1e-5f);

    unsigned int ow[4];
#pragma unroll
    for (int q = 0; q < 4; q++) {
        float w0 = nw[tid * 8 + q * 2];
        float w1 = nw[tid * 8 + q * 2 + 1];
        unsigned short o0 = f2bf(g[q * 2] * rinv * w0);
        unsigned short o1 = f2bf(g[q * 2 + 1] * rinv * w1);
        ow[q] = (unsigned int)o0 | ((unsigned int)o1 << 16);
    }
    *reinterpret_cast<uint4*>(&yy[(size_t)row * DINNER_ + tid * 8]) =
        make_uint4(ow[0], ow[1], ow[2], ow[3]);
}

// ---------------------------------------------------------------------------

extern "C" void kernel_launch(void* const* d_in, const int* in_sizes, int n_in,
                              void* d_out, int out_size, void* d_ws, size_t ws_size,
                              hipStream_t stream)
{
    const float* X    = (const float*)d_in[0];
    const float* Wip  = (const float*)d_in[1];
    const float* cw   = (const float*)d_in[2];
    const float* cb   = (const float*)d_in[3];
    const float* dtb  = (const float*)d_in[4];
    const float* Alog = (const float*)d_in[5];
    const float* Dp   = (const float*)d_in[6];
    const float* nw   = (const float*)d_in[7];
    const float* Wop  = (const float*)d_in[8];
    const float* Wth  = (const float*)d_in[9];
    float* out = (float*)d_out;

    // ws layout (~106.5 MB):
    //   zbuf  [0)           M x 2048 bf16 = 33,554,432   (gemm1 -> gate)
    //   xr    [33554432)    M x 2208 bf16 = 36,175,872   (gemm1 -> passA)
    //         Hbuf aliases xr (gemm2 -> gemm3)
    //   Yg    [69730304)    M x 2048 bf16 = 33,554,432   (passA -> gemm2)
    //   Cg    [103284736)   M x 64 bf16   =  1,048,576   (passA -> passC)
    //   wcumG [104333312)   4096 x 64 f32 =  2,097,152   (passA -> passC)
    //   Eg    [106430464)   4096 f32      =     16,384   (passA -> passB)
    // Sg lives in d_out (16,777,216 f32 = exactly out_size) until gemm3.
    char* ws = (char*)d_ws;
    bf16*  zbuf  = (bf16*) (ws);
    bf16*  xr    = (bf16*) (ws + 33554432);
    bf16*  Hbuf  = (bf16*) (ws + 33554432);
    bf16*  Yg    = (bf16*) (ws + 69730304);
    bf16*  Cg    = (bf16*) (ws + 103284736);
    float* wcumG = (float*)(ws + 104333312);
    float* Eg    = (float*)(ws + 106430464);
    float* Sg    = (float*)d_out;

    dim3 blk(256);

    // 1) zxbcdt = X @ in_proj^T; split: z -> zbuf, xBC+dt_raw -> xr
    gemm_bt<float, float, bf16><<<dim3((DIP_ + 127) / 128, M_ / 128), blk, 0, stream>>>(
        X, Wip, zbuf, xr, M_, DIP_, DIM_, DINNER_, DINNER_, XRW_);

    // 2) chunked scan
    chunk_intra_k<<<B_ * NC_ * NH_, blk, 0, stream>>>(
        xr, cw, cb, dtb, Alog, Dp, Yg, Sg, Cg, wcumG, Eg);
    chunk_state_k<<<256, blk, 0, stream>>>(Sg, Eg);
    chunk_inter_k<<<B_ * NC_ * NH_, blk, 0, stream>>>(Cg, Sg, wcumG, Yg);

    // 3) gate + RMSNorm in place on Yg
    gate_norm_k<<<M_, blk, 0, stream>>>(Yg, zbuf, nw);

    // 4) H = ynorm @ out_proj^T -> Hbuf (xr dead)
    gemm_bt<bf16, float, bf16><<<dim3(DIM_ / 128, M_ / 128), blk, 0, stream>>>(
        Yg, Wop, Hbuf, Hbuf, M_, DIM_, DINNER_, DIM_, DIM_, DIM_);

    // 5) HKV = H @ to_h^T; f32 split HK | HV into d_out (Sg dead)
    gemm_bt<bf16, float, float><<<dim3(DINNER_ / 128, M_ / 128), blk, 0, stream>>>(
        Hbuf, Wth, out, out + (size_t)M_ * DIM_, M_, DINNER_, DIM_, DIM_, DIM_, DIM_);
}

// Round 8
// 543.970 us; speedup vs baseline: 3.9269x; 1.4328x over previous
//
#include <hip/hip_runtime.h>
#include <hip/hip_bf16.h>
#include <math.h>

#define B_       2
#define L_       4096
#define DIM_     1024
#define DINNER_  2048
#define DSTATE_  64
#define NH_      32
#define HD_      64
#define CONVDIM_ 2176
#define DIP_     4256
#define M_       (B_*L_)   // 8192
#define XRW_     2208      // xr row width: xBC raw (2176) + dt_raw (32)
#define NC_      64        // chunks (L/64)

typedef __attribute__((ext_vector_type(8))) short short8;
typedef __attribute__((ext_vector_type(4))) float floatx4;
typedef __hip_bfloat16 bf16;

__device__ __forceinline__ float bf2f(unsigned short u) {
    unsigned int v = ((unsigned int)u) << 16;
    return __builtin_bit_cast(float, v);
}
__device__ __forceinline__ unsigned short f2bf(float f) {
    unsigned int x = __builtin_bit_cast(unsigned int, f);
    unsigned int lsb = (x >> 16) & 1u;
    x += 0x7fffu + lsb;
    return (unsigned short)(x >> 16);
}
__device__ __forceinline__ void storeo(bf16* p, float v) {
    *reinterpret_cast<unsigned short*>(p) = f2bf(v);
}
__device__ __forceinline__ void storeo(float* p, float v) { *p = v; }

// async global->LDS, 16 B per lane, dest = wave-uniform base + lane*16
__device__ __forceinline__ void gl2lds16(const bf16* g, short* lds) {
    __builtin_amdgcn_global_load_lds(
        (const __attribute__((address_space(1))) void*)g,
        (__attribute__((address_space(3))) void*)lds, 16, 0, 0);
}

// ---------------------------------------------------------------------------
// Cast f32 -> bf16, 8 elements/thread; n must be a multiple of 2048.
// ---------------------------------------------------------------------------
__global__ __launch_bounds__(256) void cast_f32_bf16_k(
    const float* __restrict__ src, bf16* __restrict__ dst)
{
    size_t i0 = ((size_t)blockIdx.x * 256 + threadIdx.x) * 8;
    uint4 a = *reinterpret_cast<const uint4*>(src + i0);
    uint4 b = *reinterpret_cast<const uint4*>(src + i0 + 4);
    unsigned int w0 = (unsigned int)f2bf(__builtin_bit_cast(float, a.x)) |
                      ((unsigned int)f2bf(__builtin_bit_cast(float, a.y)) << 16);
    unsigned int w1 = (unsigned int)f2bf(__builtin_bit_cast(float, a.z)) |
                      ((unsigned int)f2bf(__builtin_bit_cast(float, a.w)) << 16);
    unsigned int w2 = (unsigned int)f2bf(__builtin_bit_cast(float, b.x)) |
                      ((unsigned int)f2bf(__builtin_bit_cast(float, b.y)) << 16);
    unsigned int w3 = (unsigned int)f2bf(__builtin_bit_cast(float, b.z)) |
                      ((unsigned int)f2bf(__builtin_bit_cast(float, b.w)) << 16);
    *reinterpret_cast<uint4*>(reinterpret_cast<unsigned short*>(dst) + i0) =
        make_uint4(w0, w1, w2, w3);
}

// ---------------------------------------------------------------------------
// bf16 GEMM, m97 structure: C[m,n] = sum_k A[m,k]*W[n,k].
// 128x128 tile, 4 waves 2x2, mfma 16x16x32, BK=64, global_load_lds width=16,
// unpadded 128x64 LDS tiles (stride 64 shorts). W buffer must have >=
// ceil(N/128)*128 valid (readable) rows. Epilogue split as before.
// ---------------------------------------------------------------------------
template <typename TO>
__global__ __launch_bounds__(256) void gemm_bt16(
    const bf16* __restrict__ A, const bf16* __restrict__ W,
    TO* __restrict__ outA, TO* __restrict__ outB,
    int M, int N, int K, int split, int strideA, int strideB)
{
    __shared__ short As[128*64];
    __shared__ short Ws[128*64];
    const int tid  = threadIdx.x;
    const int m0   = blockIdx.y * 128;
    const int n0   = blockIdx.x * 128;
    const int wave = tid >> 6;
    const int lane = tid & 63;
    const int wm   = (wave >> 1) * 64;
    const int wn   = (wave & 1) * 64;
    const int ln   = lane & 15;
    const int quad = lane >> 4;
    const int lr   = lane >> 3;        // staging: row within 8-row group
    const int lc   = (lane & 7) * 8;   // staging: col (shorts)

    floatx4 acc[4][4];
#pragma unroll
    for (int i = 0; i < 4; i++)
#pragma unroll
        for (int j = 0; j < 4; j++) acc[i][j] = (floatx4){0.f, 0.f, 0.f, 0.f};

    for (int k0 = 0; k0 < K; k0 += 64) {
#pragma unroll
        for (int it = 0; it < 4; it++) {
            int ig = wave * 4 + it;               // 0..15, rows [ig*8, ig*8+8)
            gl2lds16(A + (size_t)(m0 + ig * 8 + lr) * K + k0 + lc, &As[ig * 512]);
            gl2lds16(W + (size_t)(n0 + ig * 8 + lr) * K + k0 + lc, &Ws[ig * 512]);
        }
        __syncthreads();
#pragma unroll
        for (int kk = 0; kk < 64; kk += 32) {
            short8 af[4], bfv[4];
#pragma unroll
            for (int i = 0; i < 4; i++)
                af[i] = *reinterpret_cast<const short8*>(&As[(wm + i * 16 + ln) * 64 + kk + quad * 8]);
#pragma unroll
            for (int j = 0; j < 4; j++)
                bfv[j] = *reinterpret_cast<const short8*>(&Ws[(wn + j * 16 + ln) * 64 + kk + quad * 8]);
#pragma unroll
            for (int i = 0; i < 4; i++)
#pragma unroll
                for (int j = 0; j < 4; j++)
                    acc[i][j] = __builtin_amdgcn_mfma_f32_16x16x32_bf16(af[i], bfv[j], acc[i][j], 0, 0, 0);
        }
        __syncthreads();
    }

#pragma unroll
    for (int i = 0; i < 4; i++)
#pragma unroll
        for (int j = 0; j < 4; j++)
#pragma unroll
            for (int r = 0; r < 4; r++) {
                int grow = m0 + wm + i * 16 + quad * 4 + r;
                int gcol = n0 + wn + j * 16 + ln;
                if (gcol < N) {
                    if (gcol < split)
                        storeo(outA + (size_t)grow * strideA + gcol, acc[i][j][r]);
                    else
                        storeo(outB + (size_t)grow * strideB + (gcol - split), acc[i][j][r]);
                }
            }
}

// ---------------------------------------------------------------------------
// Pass A: per (b,chunk,h): fused conv+silu+softplus + 3 MFMA 64^3 GEMMs.
// (unchanged from round 7 — validated)
// ---------------------------------------------------------------------------
__global__ __launch_bounds__(256) void chunk_intra_k(
    const bf16* __restrict__ xr,
    const float* __restrict__ cw, const float* __restrict__ cb,
    const float* __restrict__ dtb, const float* __restrict__ A_log,
    const float* __restrict__ Dp,
    bf16* __restrict__ Yg, float* __restrict__ Sg, bf16* __restrict__ Cg,
    float* __restrict__ wcumG, float* __restrict__ Eg)
{
    __shared__ short Bst[64*72];
    __shared__ short Cst[64*72];
    __shared__ short xT [64*72];
    __shared__ short BwT[64*72];
    __shared__ unsigned short raw[3*67*64];
    __shared__ float wXc[256], wBc[256], wCc[256];
    __shared__ float bXc[64], bBc[64], bCc[64];
    __shared__ float dts[64], cums[64], wS[64], wcumS[64];

    const int tid  = threadIdx.x;
    const int bid  = blockIdx.x;
    const int h    = bid & 31;
    const int bc   = bid >> 5;
    const int c    = bc & 63;
    const int b    = bc >> 6;
    const int xch0 = h * 64;
    const unsigned short* xru = (const unsigned short*)xr;

    const float Ah   = -__expf(A_log[h]);
    const float Dh   = Dp[h];
    const float dtbh = dtb[h];

    { int n = tid >> 2, j = tid & 3;
      wXc[tid] = cw[(xch0 + n) * 4 + j];
      wBc[tid] = cw[(2048 + n) * 4 + j];
      wCc[tid] = cw[(2112 + n) * 4 + j]; }
    if (tid < 64) { bXc[tid] = cb[xch0 + tid]; bBc[tid] = cb[2048 + tid]; bCc[tid] = cb[2112 + tid]; }

    for (int q = tid; q < 536; q += 256) {
        int r = q >> 3, c8 = (q & 7) * 8;
        int rt = c * 64 - 3 + r;
        uint4 vX = make_uint4(0u,0u,0u,0u), vB = vX, vC = vX;
        if (rt >= 0) {
            size_t ro = (size_t)(b * L_ + rt) * XRW_;
            vX = *reinterpret_cast<const uint4*>(xru + ro + xch0 + c8);
            vB = *reinterpret_cast<const uint4*>(xru + ro + 2048 + c8);
            vC = *reinterpret_cast<const uint4*>(xru + ro + 2112 + c8);
        }
        *reinterpret_cast<uint4*>(&raw[r*64 + c8])        = vX;
        *reinterpret_cast<uint4*>(&raw[4288 + r*64 + c8]) = vB;
        *reinterpret_cast<uint4*>(&raw[8576 + r*64 + c8]) = vC;
    }
    if (tid < 64) {
        float v = bf2f(xru[(size_t)(b * L_ + c * 64 + tid) * XRW_ + 2176 + h]) + dtbh;
        dts[tid] = fmaxf(v, 0.f) + log1pf(__expf(-fabsf(v)));
    }
    __syncthreads();

    if (tid == 0) {
        float cc = 0.f;
        for (int t = 0; t < 64; t++) { cc += dts[t] * Ah; cums[t] = cc; }
    }
    __syncthreads();
    if (tid < 64) {
        wS[tid]    = __expf(cums[63] - cums[tid]) * dts[tid];
        wcumS[tid] = __expf(cums[tid]);
        wcumG[(size_t)bid * 64 + tid] = wcumS[tid];
    }
    if (tid == 0) Eg[bid] = __expf(cums[63]);
    __syncthreads();

    for (int q = tid; q < 12288; q += 256) {
        int mtx = q >> 12;
        int qq  = q & 4095;
        int s = qq >> 6, ch = qq & 63;
        if (mtx == 0) {
            float a = bBc[ch];
#pragma unroll
            for (int j = 0; j < 4; j++) a = fmaf(bf2f(raw[4288 + (s+j)*64 + ch]), wBc[ch*4+j], a);
            float sv = a / (1.f + __expf(-a));
            Bst[s*72 + ch] = f2bf(sv);
            BwT[ch*72 + s] = f2bf(sv * wS[s]);
        } else if (mtx == 1) {
            float a = bCc[ch];
#pragma unroll
            for (int j = 0; j < 4; j++) a = fmaf(bf2f(raw[8576 + (s+j)*64 + ch]), wCc[ch*4+j], a);
            float sv = a / (1.f + __expf(-a));
            unsigned short u = f2bf(sv);
            Cst[s*72 + ch] = u;
            if (h == 0) ((unsigned short*)Cg)[(size_t)(b*L_ + c*64 + s)*64 + ch] = u;
        } else {
            float a = bXc[ch];
#pragma unroll
            for (int j = 0; j < 4; j++) a = fmaf(bf2f(raw[(s+j)*64 + ch]), wXc[ch*4+j], a);
            float sv = a / (1.f + __expf(-a));
            xT[ch*72 + s] = f2bf(sv);
        }
    }
    __syncthreads();

    const int wave = tid >> 6, lane = tid & 63;
    const int ln = lane & 15, quad = lane >> 4;
    const int wm = (wave >> 1) * 32, wn = (wave & 1) * 32;

    floatx4 accG[2][2];
#pragma unroll
    for (int i = 0; i < 2; i++)
#pragma unroll
        for (int j = 0; j < 2; j++) accG[i][j] = (floatx4){0.f,0.f,0.f,0.f};
#pragma unroll
    for (int kk = 0; kk < 64; kk += 32) {
        short8 af[2], bfv[2];
#pragma unroll
        for (int i = 0; i < 2; i++)
            af[i] = *reinterpret_cast<const short8*>(&Cst[(wm + i*16 + ln)*72 + kk + quad*8]);
#pragma unroll
        for (int j = 0; j < 2; j++)
            bfv[j] = *reinterpret_cast<const short8*>(&Bst[(wn + j*16 + ln)*72 + kk + quad*8]);
#pragma unroll
        for (int i = 0; i < 2; i++)
#pragma unroll
            for (int j = 0; j < 2; j++)
                accG[i][j] = __builtin_amdgcn_mfma_f32_16x16x32_bf16(af[i], bfv[j], accG[i][j], 0,0,0);
    }
    short* Mm = (short*)raw;
#pragma unroll
    for (int i = 0; i < 2; i++)
#pragma unroll
        for (int j = 0; j < 2; j++)
#pragma unroll
            for (int r = 0; r < 4; r++) {
                int t = wm + i*16 + quad*4 + r;
                int s = wn + j*16 + ln;
                float v = (s <= t) ? __expf(cums[t] - cums[s]) * dts[s] * accG[i][j][r] : 0.f;
                Mm[t*72 + s] = (short)f2bf(v);
            }
    __syncthreads();

    floatx4 accY[2][2];
#pragma unroll
    for (int i = 0; i < 2; i++)
#pragma unroll
        for (int j = 0; j < 2; j++) accY[i][j] = (floatx4){0.f,0.f,0.f,0.f};
#pragma unroll
    for (int kk = 0; kk < 64; kk += 32) {
        short8 af[2], bfv[2];
#pragma unroll
        for (int i = 0; i < 2; i++)
            af[i] = *reinterpret_cast<const short8*>(&Mm[(wm + i*16 + ln)*72 + kk + quad*8]);
#pragma unroll
        for (int j = 0; j < 2; j++)
            bfv[j] = *reinterpret_cast<const short8*>(&xT[(wn + j*16 + ln)*72 + kk + quad*8]);
#pragma unroll
        for (int i = 0; i < 2; i++)
#pragma unroll
            for (int j = 0; j < 2; j++)
                accY[i][j] = __builtin_amdgcn_mfma_f32_16x16x32_bf16(af[i], bfv[j], accY[i][j], 0,0,0);
    }
    unsigned short* Yu = (unsigned short*)Yg;
#pragma unroll
    for (int i = 0; i < 2; i++)
#pragma unroll
        for (int j = 0; j < 2; j++)
#pragma unroll
            for (int r = 0; r < 4; r++) {
                int t = wm + i*16 + quad*4 + r;
                int p = wn + j*16 + ln;
                float yv = accY[i][j][r] + Dh * bf2f((unsigned short)xT[p*72 + t]);
                Yu[(size_t)(b*L_ + c*64 + t)*DINNER_ + xch0 + p] = f2bf(yv);
            }

    floatx4 accS[2][2];
#pragma unroll
    for (int i = 0; i < 2; i++)
#pragma unroll
        for (int j = 0; j < 2; j++) accS[i][j] = (floatx4){0.f,0.f,0.f,0.f};
#pragma unroll
    for (int kk = 0; kk < 64; kk += 32) {
        short8 af[2], bfv[2];
#pragma unroll
        for (int i = 0; i < 2; i++)
            af[i] = *reinterpret_cast<const short8*>(&xT[(wm + i*16 + ln)*72 + kk + quad*8]);
#pragma unroll
        for (int j = 0; j < 2; j++)
            bfv[j] = *reinterpret_cast<const short8*>(&BwT[(wn + j*16 + ln)*72 + kk + quad*8]);
#pragma unroll
        for (int i = 0; i < 2; i++)
#pragma unroll
            for (int j = 0; j < 2; j++)
                accS[i][j] = __builtin_amdgcn_mfma_f32_16x16x32_bf16(af[i], bfv[j], accS[i][j], 0,0,0);
    }
#pragma unroll
    for (int i = 0; i < 2; i++)
#pragma unroll
        for (int j = 0; j < 2; j++)
#pragma unroll
            for (int r = 0; r < 4; r++) {
                int p = wm + i*16 + quad*4 + r;
                int n = wn + j*16 + ln;
                Sg[(size_t)bid * 4096 + p*64 + n] = accS[i][j][r];
            }
}

// ---------------------------------------------------------------------------
// Pass B: prefix over chunks (unchanged)
// ---------------------------------------------------------------------------
__global__ __launch_bounds__(256) void chunk_state_k(
    float* __restrict__ Sg, const float* __restrict__ Eg)
{
    int g  = blockIdx.x * 1024 + threadIdx.x * 4;
    int bh = g >> 12;
    int b  = bh >> 5, h = bh & 31;
    int e  = g & 4095;
    float4 run = make_float4(0.f, 0.f, 0.f, 0.f);
    for (int c = 0; c < NC_; c++) {
        int bid = (b * 64 + c) * 32 + h;
        size_t idx = (size_t)bid * 4096 + e;
        float4 s = *reinterpret_cast<float4*>(&Sg[idx]);
        float  E = Eg[bid];
        *reinterpret_cast<float4*>(&Sg[idx]) = run;
        run.x = run.x * E + s.x;
        run.y = run.y * E + s.y;
        run.z = run.z * E + s.z;
        run.w = run.w * E + s.w;
    }
}

// ---------------------------------------------------------------------------
// Pass C: Y += wcum[t] * C·hprev^T (unchanged)
// ---------------------------------------------------------------------------
__global__ __launch_bounds__(256) void chunk_inter_k(
    const bf16* __restrict__ Cg, const float* __restrict__ Sg,
    const float* __restrict__ wcumG, bf16* __restrict__ Yg)
{
    __shared__ short Cst[64*72];
    __shared__ short hpT[64*72];
    __shared__ float wcumL[64];

    const int tid = threadIdx.x;
    const int bid = blockIdx.x;
    const int h   = bid & 31;
    const int bc  = bid >> 5;
    const int c   = bc & 63;
    const int b   = bc >> 6;

    for (int q = tid; q < 512; q += 256) {
        int r = q >> 3, c8 = (q & 7) * 8;
        *reinterpret_cast<uint4*>(&Cst[r*72 + c8]) =
            *reinterpret_cast<const uint4*>((const unsigned short*)Cg + (size_t)(b*L_ + c*64 + r)*64 + c8);
    }
    for (int q = tid; q < 1024; q += 256) {
        int p = q >> 4, n4 = (q & 15) * 4;
        float4 v = *reinterpret_cast<const float4*>(&Sg[(size_t)bid * 4096 + p*64 + n4]);
        unsigned int lo = (unsigned int)f2bf(v.x) | ((unsigned int)f2bf(v.y) << 16);
        unsigned int hi = (unsigned int)f2bf(v.z) | ((unsigned int)f2bf(v.w) << 16);
        *reinterpret_cast<uint2*>(&hpT[p*72 + n4]) = make_uint2(lo, hi);
    }
    if (tid < 64) wcumL[tid] = wcumG[(size_t)bid * 64 + tid];
    __syncthreads();

    const int wave = tid >> 6, lane = tid & 63;
    const int ln = lane & 15, quad = lane >> 4;
    const int wm = (wave >> 1) * 32, wn = (wave & 1) * 32;

    floatx4 acc[2][2];
#pragma unroll
    for (int i = 0; i < 2; i++)
#pragma unroll
        for (int j = 0; j < 2; j++) acc[i][j] = (floatx4){0.f,0.f,0.f,0.f};
#pragma unroll
    for (int kk = 0; kk < 64; kk += 32) {
        short8 af[2], bfv[2];
#pragma unroll
        for (int i = 0; i < 2; i++)
            af[i] = *reinterpret_cast<const short8*>(&Cst[(wm + i*16 + ln)*72 + kk + quad*8]);
#pragma unroll
        for (int j = 0; j < 2; j++)
            bfv[j] = *reinterpret_cast<const short8*>(&hpT[(wn + j*16 + ln)*72 + kk + quad*8]);
#pragma unroll
        for (int i = 0; i < 2; i++)
#pragma unroll
            for (int j = 0; j < 2; j++)
                acc[i][j] = __builtin_amdgcn_mfma_f32_16x16x32_bf16(af[i], bfv[j], acc[i][j], 0,0,0);
    }
    unsigned short* Yu = (unsigned short*)Yg;
#pragma unroll
    for (int i = 0; i < 2; i++)
#pragma unroll
        for (int j = 0; j < 2; j++)
#pragma unroll
            for (int r = 0; r < 4; r++) {
                int t = wm + i*16 + quad*4 + r;
                int p = wn + j*16 + ln;
                size_t idx = (size_t)(b*L_ + c*64 + t)*DINNER_ + h*64 + p;
                float yv = bf2f(Yu[idx]) + wcumL[t] * acc[i][j][r];
                Yu[idx] = f2bf(yv);
            }
}

// ---------------------------------------------------------------------------
// gate + RMSNorm (unchanged)
// ---------------------------------------------------------------------------
__global__ __launch_bounds__(256) void gate_norm_k(
    bf16* __restrict__ y, const bf16* __restrict__ zbuf, const float* __restrict__ nw)
{
    __shared__ float red[4];
    int row = blockIdx.x;
    int tid = threadIdx.x;
    unsigned short* yy = (unsigned short*)y;
    const unsigned short* zz = (const unsigned short*)zbuf;

    uint4 yv = *reinterpret_cast<uint4*>(&yy[(size_t)row * DINNER_ + tid * 8]);
    uint4 zv = *reinterpret_cast<const uint4*>(&zz[(size_t)row * DINNER_ + tid * 8]);
    unsigned int yw[4] = {yv.x, yv.y, yv.z, yv.w};
    unsigned int zw[4] = {zv.x, zv.y, zv.z, zv.w};
    float g[8];
    float ss = 0.f;
#pragma unroll
    for (int q = 0; q < 4; q++) {
        float y0 = bf2f((unsigned short)(yw[q] & 0xffffu)), y1 = bf2f((unsigned short)(yw[q] >> 16));
        float z0 = bf2f((unsigned short)(zw[q] & 0xffffu)), z1 = bf2f((unsigned short)(zw[q] >> 16));
        float g0 = y0 * (z0 / (1.f + __expf(-z0)));
        float g1 = y1 * (z1 / (1.f + __expf(-z1)));
        g[q * 2] = g0; g[q * 2 + 1] = g1;
        ss += g0 * g0 + g1 * g1;
    }
#pragma unroll
    for (int o = 1; o < 64; o <<= 1) ss += __shfl_xor(ss, o);
    if ((tid & 63) == 0) red[tid >> 6] = ss;
    __syncthreads();
    float tot = red[0] + red[1] + red[2] + red[3];
    float rinv = rsqrtf(tot * (1.f / DINNER_) + 1e-5f);

    unsigned int ow[4];
#pragma unroll
    for (int q = 0; q < 4; q++) {
        float w0 = nw[tid * 8 + q * 2];
        float w1 = nw[tid * 8 + q * 2 + 1];
        unsigned short o0 = f2bf(g[q * 2] * rinv * w0);
        unsigned short o1 = f2bf(g[q * 2 + 1] * rinv * w1);
        ow[q] = (unsigned int)o0 | ((unsigned int)o1 << 16);
    }
    *reinterpret_cast<uint4*>(&yy[(size_t)row * DINNER_ + tid * 8]) =
        make_uint4(ow[0], ow[1], ow[2], ow[3]);
}

// ---------------------------------------------------------------------------

extern "C" void kernel_launch(void* const* d_in, const int* in_sizes, int n_in,
                              void* d_out, int out_size, void* d_ws, size_t ws_size,
                              hipStream_t stream)
{
    const float* X    = (const float*)d_in[0];
    const float* Wip  = (const float*)d_in[1];
    const float* cw   = (const float*)d_in[2];
    const float* cb   = (const float*)d_in[3];
    const float* dtb  = (const float*)d_in[4];
    const float* Alog = (const float*)d_in[5];
    const float* Dp   = (const float*)d_in[6];
    const float* nw   = (const float*)d_in[7];
    const float* Wop  = (const float*)d_in[8];
    const float* Wth  = (const float*)d_in[9];
    float* out = (float*)d_out;

    // ws layout (~106.5 MB, same ceiling as validated round 7):
    //   zbuf  [0)          M x 2048 bf16 = 33,554,432  (gemm1 -> gate_norm)
    //         Wopb aliases zbuf[0)        4,194,304    (cast after gate -> gemm2)
    //         Wthb aliases zbuf[4194304)  4,194,304    (cast after gate -> gemm3)
    //   xr    [33554432)   M x 2208 bf16 = 36,175,872  (gemm1 -> chunk_intra)
    //         Hbuf aliases xr (gemm2 -> gemm3)
    //   Yg    [69730304)   M x 2048 bf16 = 33,554,432  (chunk_intra -> gemm2)
    //         Xb   aliases Yg[0)        16,777,216     (cast -> gemm1)
    //         Wipb aliases Yg[16777216)  8,912,896 (4352 rows, padded) (cast -> gemm1)
    //   Cg    [103284736)  M x 64 bf16   =  1,048,576
    //   wcumG [104333312)  4096x64 f32   =  2,097,152
    //   Eg    [106430464)  4096 f32      =     16,384
    // Sg lives in d_out (dead before gemm3 overwrites d_out).
    char* ws = (char*)d_ws;
    bf16*  zbuf  = (bf16*) (ws);
    bf16*  Wopb  = (bf16*) (ws);
    bf16*  Wthb  = (bf16*) (ws + 4194304);
    bf16*  xr    = (bf16*) (ws + 33554432);
    bf16*  Hbuf  = (bf16*) (ws + 33554432);
    bf16*  Yg    = (bf16*) (ws + 69730304);
    bf16*  Xb    = (bf16*) (ws + 69730304);
    bf16*  Wipb  = (bf16*) (ws + 69730304 + 16777216);
    bf16*  Cg    = (bf16*) (ws + 103284736);
    float* wcumG = (float*)(ws + 104333312);
    float* Eg    = (float*)(ws + 106430464);
    float* Sg    = (float*)d_out;

    dim3 blk(256);

    // 0) cast X and in_proj weights to bf16 (Wipb padded to 4352 rows; the
    //    pad rows hold poison, read-only garbage whose output cols are never stored)
    cast_f32_bf16_k<<<(M_ * DIM_) / 2048, blk, 0, stream>>>(X, Xb);
    cast_f32_bf16_k<<<(DIP_ * DIM_) / 2048, blk, 0, stream>>>(Wip, Wipb);

    // 1) zxbcdt = Xb @ Wipb^T; split: z -> zbuf, xBC+dt_raw -> xr
    gemm_bt16<bf16><<<dim3(34, M_ / 128), blk, 0, stream>>>(
        Xb, Wipb, zbuf, xr, M_, DIP_, DIM_, DINNER_, DINNER_, XRW_);

    // 2) chunked scan
    chunk_intra_k<<<B_ * NC_ * NH_, blk, 0, stream>>>(
        xr, cw, cb, dtb, Alog, Dp, Yg, Sg, Cg, wcumG, Eg);
    chunk_state_k<<<256, blk, 0, stream>>>(Sg, Eg);
    chunk_inter_k<<<B_ * NC_ * NH_, blk, 0, stream>>>(Cg, Sg, wcumG, Yg);

    // 3) gate + RMSNorm in place on Yg (last read of zbuf)
    gate_norm_k<<<M_, blk, 0, stream>>>(Yg, zbuf, nw);

    // 3b) cast out_proj / to_h weights into the now-dead zbuf region
    cast_f32_bf16_k<<<(DIM_ * DINNER_) / 2048, blk, 0, stream>>>(Wop, Wopb);
    cast_f32_bf16_k<<<(DINNER_ * DIM_) / 2048, blk, 0, stream>>>(Wth, Wthb);

    // 4) H = ynorm @ out_proj^T -> Hbuf (xr dead)
    gemm_bt16<bf16><<<dim3(DIM_ / 128, M_ / 128), blk, 0, stream>>>(
        Yg, Wopb, Hbuf, Hbuf, M_, DIM_, DINNER_, DIM_, DIM_, DIM_);

    // 5) HKV = H @ to_h^T; f32 split HK | HV into d_out (Sg dead)
    gemm_bt16<float><<<dim3(DINNER_ / 128, M_ / 128), blk, 0, stream>>>(
        Hbuf, Wthb, out, out + (size_t)M_ * DIM_, M_, DINNER_, DIM_, DIM_, DIM_, DIM_);
}

// Round 9
// 513.827 us; speedup vs baseline: 4.1573x; 1.0587x over previous
//
#include <hip/hip_runtime.h>
#include <hip/hip_bf16.h>
#include <math.h>

#define B_       2
#define L_       4096
#define DIM_     1024
#define DINNER_  2048
#define DSTATE_  64
#define NH_      32
#define HD_      64
#define CONVDIM_ 2176
#define DIP_     4256
#define M_       (B_*L_)   // 8192
#define XRW_     2208      // xr row width: xBC raw (2176) + dt_raw (32)
#define NC_      64        // chunks (L/64)

typedef __attribute__((ext_vector_type(8))) short short8;
typedef __attribute__((ext_vector_type(4))) float floatx4;
typedef __hip_bfloat16 bf16;

__device__ __forceinline__ float bf2f(unsigned short u) {
    unsigned int v = ((unsigned int)u) << 16;
    return __builtin_bit_cast(float, v);
}
__device__ __forceinline__ unsigned short f2bf(float f) {
    unsigned int x = __builtin_bit_cast(unsigned int, f);
    unsigned int lsb = (x >> 16) & 1u;
    x += 0x7fffu + lsb;
    return (unsigned short)(x >> 16);
}
__device__ __forceinline__ void storeo(bf16* p, float v) {
    *reinterpret_cast<unsigned short*>(p) = f2bf(v);
}
__device__ __forceinline__ void storeo(float* p, float v) { *p = v; }

__device__ __forceinline__ void gl2lds16(const bf16* g, short* lds) {
    __builtin_amdgcn_global_load_lds(
        (const __attribute__((address_space(1))) void*)g,
        (__attribute__((address_space(3))) void*)lds, 16, 0, 0);
}

// ---------------------------------------------------------------------------
// Cast f32 -> bf16, 8 elements/thread; n multiple of 2048.
// ---------------------------------------------------------------------------
__global__ __launch_bounds__(256) void cast_f32_bf16_k(
    const float* __restrict__ src, bf16* __restrict__ dst)
{
    size_t i0 = ((size_t)blockIdx.x * 256 + threadIdx.x) * 8;
    uint4 a = *reinterpret_cast<const uint4*>(src + i0);
    uint4 b = *reinterpret_cast<const uint4*>(src + i0 + 4);
    unsigned int w0 = (unsigned int)f2bf(__builtin_bit_cast(float, a.x)) |
                      ((unsigned int)f2bf(__builtin_bit_cast(float, a.y)) << 16);
    unsigned int w1 = (unsigned int)f2bf(__builtin_bit_cast(float, a.z)) |
                      ((unsigned int)f2bf(__builtin_bit_cast(float, a.w)) << 16);
    unsigned int w2 = (unsigned int)f2bf(__builtin_bit_cast(float, b.x)) |
                      ((unsigned int)f2bf(__builtin_bit_cast(float, b.y)) << 16);
    unsigned int w3 = (unsigned int)f2bf(__builtin_bit_cast(float, b.z)) |
                      ((unsigned int)f2bf(__builtin_bit_cast(float, b.w)) << 16);
    *reinterpret_cast<uint4*>(reinterpret_cast<unsigned short*>(dst) + i0) =
        make_uint4(w0, w1, w2, w3);
}

// ---------------------------------------------------------------------------
// bf16 GEMM, m97 structure (validated round 8).
// ---------------------------------------------------------------------------
template <typename TO>
__global__ __launch_bounds__(256) void gemm_bt16(
    const bf16* __restrict__ A, const bf16* __restrict__ W,
    TO* __restrict__ outA, TO* __restrict__ outB,
    int M, int N, int K, int split, int strideA, int strideB)
{
    __shared__ short As[128*64];
    __shared__ short Ws[128*64];
    const int tid  = threadIdx.x;
    const int m0   = blockIdx.y * 128;
    const int n0   = blockIdx.x * 128;
    const int wave = tid >> 6;
    const int lane = tid & 63;
    const int wm   = (wave >> 1) * 64;
    const int wn   = (wave & 1) * 64;
    const int ln   = lane & 15;
    const int quad = lane >> 4;
    const int lr   = lane >> 3;
    const int lc   = (lane & 7) * 8;

    floatx4 acc[4][4];
#pragma unroll
    for (int i = 0; i < 4; i++)
#pragma unroll
        for (int j = 0; j < 4; j++) acc[i][j] = (floatx4){0.f, 0.f, 0.f, 0.f};

    for (int k0 = 0; k0 < K; k0 += 64) {
#pragma unroll
        for (int it = 0; it < 4; it++) {
            int ig = wave * 4 + it;
            gl2lds16(A + (size_t)(m0 + ig * 8 + lr) * K + k0 + lc, &As[ig * 512]);
            gl2lds16(W + (size_t)(n0 + ig * 8 + lr) * K + k0 + lc, &Ws[ig * 512]);
        }
        __syncthreads();
#pragma unroll
        for (int kk = 0; kk < 64; kk += 32) {
            short8 af[4], bfv[4];
#pragma unroll
            for (int i = 0; i < 4; i++)
                af[i] = *reinterpret_cast<const short8*>(&As[(wm + i * 16 + ln) * 64 + kk + quad * 8]);
#pragma unroll
            for (int j = 0; j < 4; j++)
                bfv[j] = *reinterpret_cast<const short8*>(&Ws[(wn + j * 16 + ln) * 64 + kk + quad * 8]);
#pragma unroll
            for (int i = 0; i < 4; i++)
#pragma unroll
                for (int j = 0; j < 4; j++)
                    acc[i][j] = __builtin_amdgcn_mfma_f32_16x16x32_bf16(af[i], bfv[j], acc[i][j], 0, 0, 0);
        }
        __syncthreads();
    }

#pragma unroll
    for (int i = 0; i < 4; i++)
#pragma unroll
        for (int j = 0; j < 4; j++)
#pragma unroll
            for (int r = 0; r < 4; r++) {
                int grow = m0 + wm + i * 16 + quad * 4 + r;
                int gcol = n0 + wn + j * 16 + ln;
                if (gcol < N) {
                    if (gcol < split)
                        storeo(outA + (size_t)grow * strideA + gcol, acc[i][j][r]);
                    else
                        storeo(outB + (size_t)grow * strideB + (gcol - split), acc[i][j][r]);
                }
            }
}

// ---------------------------------------------------------------------------
// Conv+bias+silu over ALL 2176 xBC channels, each computed once.
// thread = 8 channels of one row. Grid: M*272/256 = 8704.
// ---------------------------------------------------------------------------
__global__ __launch_bounds__(256) void conv_all_k(
    const bf16* __restrict__ xr, const float* __restrict__ cw,
    const float* __restrict__ cb, bf16* __restrict__ xc)
{
    int idx = blockIdx.x * 256 + threadIdx.x;
    int row = idx / 272;
    int ch0 = (idx - row * 272) * 8;
    int t   = row & (L_ - 1);
    const unsigned short* xru = (const unsigned short*)xr;
    uint4 rv[4];
#pragma unroll
    for (int j = 0; j < 4; j++) {
        rv[j] = make_uint4(0u, 0u, 0u, 0u);
        if (t + j - 3 >= 0)
            rv[j] = *reinterpret_cast<const uint4*>(xru + (size_t)(row + j - 3) * XRW_ + ch0);
    }
    unsigned int ow[4];
#pragma unroll
    for (int pair = 0; pair < 4; pair++) {
        unsigned short o2[2];
#pragma unroll
        for (int k = 0; k < 2; k++) {
            int cc = pair * 2 + k;
            float a = cb[ch0 + cc];
#pragma unroll
            for (int j = 0; j < 4; j++) {
                unsigned int w32 = (&rv[j].x)[cc >> 1];
                unsigned short u = (cc & 1) ? (unsigned short)(w32 >> 16)
                                            : (unsigned short)(w32 & 0xffffu);
                a = fmaf(bf2f(u), cw[(ch0 + cc) * 4 + j], a);
            }
            o2[k] = f2bf(a / (1.f + __expf(-a)));
        }
        ow[pair] = (unsigned int)o2[0] | ((unsigned int)o2[1] << 16);
    }
    *reinterpret_cast<uint4*>((unsigned short*)xc + (size_t)row * CONVDIM_ + ch0) =
        make_uint4(ow[0], ow[1], ow[2], ow[3]);
}

// ---------------------------------------------------------------------------
// dt = softplus(dt_raw + dt_bias) -> f32. Grid M*32/256.
// ---------------------------------------------------------------------------
__global__ __launch_bounds__(256) void dt_k(
    const bf16* __restrict__ xr, const float* __restrict__ dtb, float* __restrict__ dtf)
{
    int idx = blockIdx.x * 256 + threadIdx.x;
    int h  = idx & (NH_ - 1);
    int ml = idx >> 5;
    float v = bf2f(((const unsigned short*)xr)[(size_t)ml * XRW_ + 2176 + h]) + dtb[h];
    dtf[idx] = fmaxf(v, 0.f) + log1pf(__expf(-fabsf(v)));
}

// ---------------------------------------------------------------------------
// Pass A (slim): per (b,chunk,h): stage pre-activated x/B/C, 3 MFMA GEMMs.
// blockIdx.x = ((b*64+c)*32+h). LDS ~46 KB -> 3 blocks/CU.
// ---------------------------------------------------------------------------
__global__ __launch_bounds__(256) void chunk_intra_k(
    const bf16* __restrict__ xc, const float* __restrict__ dtf,
    const float* __restrict__ A_log, const float* __restrict__ Dp,
    bf16* __restrict__ Yg, float* __restrict__ Sg, float* __restrict__ Eg)
{
    __shared__ short Bst[64*72];
    __shared__ short Cst[64*72];
    __shared__ short xsM[64*72];   // x staging, then reused as masked M
    __shared__ short xT [64*72];
    __shared__ short BwT[64*72];
    __shared__ float dts[64], cums[64], wS[64];

    const int tid  = threadIdx.x;
    const int bid  = blockIdx.x;
    const int h    = bid & 31;
    const int bc   = bid >> 5;
    const int c    = bc & 63;
    const int b    = bc >> 6;
    const int xch0 = h * 64;
    const unsigned short* xcu = (const unsigned short*)xc;

    const float Ah = -__expf(A_log[h]);
    const float Dh = Dp[h];

    // stage B / C / x tiles (rows s = 0..63)
    for (int q = tid; q < 1536; q += 256) {
        int sel = q >> 9;              // 0:B 1:C 2:x
        int qq  = q & 511;
        int r = qq >> 3, c8 = (qq & 7) * 8;
        size_t ro = (size_t)(b * L_ + c * 64 + r) * CONVDIM_;
        if (sel == 0)
            *reinterpret_cast<uint4*>(&Bst[r*72 + c8]) =
                *reinterpret_cast<const uint4*>(xcu + ro + 2048 + c8);
        else if (sel == 1)
            *reinterpret_cast<uint4*>(&Cst[r*72 + c8]) =
                *reinterpret_cast<const uint4*>(xcu + ro + 2112 + c8);
        else
            *reinterpret_cast<uint4*>(&xsM[r*72 + c8]) =
                *reinterpret_cast<const uint4*>(xcu + ro + xch0 + c8);
    }
    if (tid < 64) dts[tid] = dtf[(size_t)(b * L_ + c * 64 + tid) * NH_ + h];
    __syncthreads();

    if (tid == 0) {
        float cc = 0.f;
        for (int t = 0; t < 64; t++) { cc += dts[t] * Ah; cums[t] = cc; }
    }
    __syncthreads();
    if (tid < 64) wS[tid] = __expf(cums[63] - cums[tid]) * dts[tid];
    if (tid == 0) Eg[bid] = __expf(cums[63]);
    __syncthreads();

    // transposes: xT[p][s] = x[s][p]; BwT[n][s] = B[s][n]*wS[s]
    for (int q = tid; q < 4096; q += 256) {
        int s = q & 63, ch = q >> 6;
        xT [ch*72 + s] = xsM[s*72 + ch];
        BwT[ch*72 + s] = (short)f2bf(bf2f((unsigned short)Bst[s*72 + ch]) * wS[s]);
    }
    __syncthreads();

    const int wave = tid >> 6, lane = tid & 63;
    const int ln = lane & 15, quad = lane >> 4;
    const int wm = (wave >> 1) * 32, wn = (wave & 1) * 32;

    // --- G = C · B^T ---
    floatx4 accG[2][2];
#pragma unroll
    for (int i = 0; i < 2; i++)
#pragma unroll
        for (int j = 0; j < 2; j++) accG[i][j] = (floatx4){0.f,0.f,0.f,0.f};
#pragma unroll
    for (int kk = 0; kk < 64; kk += 32) {
        short8 af[2], bfv[2];
#pragma unroll
        for (int i = 0; i < 2; i++)
            af[i] = *reinterpret_cast<const short8*>(&Cst[(wm + i*16 + ln)*72 + kk + quad*8]);
#pragma unroll
        for (int j = 0; j < 2; j++)
            bfv[j] = *reinterpret_cast<const short8*>(&Bst[(wn + j*16 + ln)*72 + kk + quad*8]);
#pragma unroll
        for (int i = 0; i < 2; i++)
#pragma unroll
            for (int j = 0; j < 2; j++)
                accG[i][j] = __builtin_amdgcn_mfma_f32_16x16x32_bf16(af[i], bfv[j], accG[i][j], 0,0,0);
    }
    __syncthreads();   // all xsM staging reads done (transpose phase) -> safe to overwrite
#pragma unroll
    for (int i = 0; i < 2; i++)
#pragma unroll
        for (int j = 0; j < 2; j++)
#pragma unroll
            for (int r = 0; r < 4; r++) {
                int t = wm + i*16 + quad*4 + r;
                int s = wn + j*16 + ln;
                float v = (s <= t) ? __expf(cums[t] - cums[s]) * dts[s] * accG[i][j][r] : 0.f;
                xsM[t*72 + s] = (short)f2bf(v);
            }
    __syncthreads();

    // --- Yintra = M · xT^T + D*x ---
    floatx4 accY[2][2];
#pragma unroll
    for (int i = 0; i < 2; i++)
#pragma unroll
        for (int j = 0; j < 2; j++) accY[i][j] = (floatx4){0.f,0.f,0.f,0.f};
#pragma unroll
    for (int kk = 0; kk < 64; kk += 32) {
        short8 af[2], bfv[2];
#pragma unroll
        for (int i = 0; i < 2; i++)
            af[i] = *reinterpret_cast<const short8*>(&xsM[(wm + i*16 + ln)*72 + kk + quad*8]);
#pragma unroll
        for (int j = 0; j < 2; j++)
            bfv[j] = *reinterpret_cast<const short8*>(&xT[(wn + j*16 + ln)*72 + kk + quad*8]);
#pragma unroll
        for (int i = 0; i < 2; i++)
#pragma unroll
            for (int j = 0; j < 2; j++)
                accY[i][j] = __builtin_amdgcn_mfma_f32_16x16x32_bf16(af[i], bfv[j], accY[i][j], 0,0,0);
    }
    unsigned short* Yu = (unsigned short*)Yg;
#pragma unroll
    for (int i = 0; i < 2; i++)
#pragma unroll
        for (int j = 0; j < 2; j++)
#pragma unroll
            for (int r = 0; r < 4; r++) {
                int t = wm + i*16 + quad*4 + r;
                int p = wn + j*16 + ln;
                float yv = accY[i][j][r] + Dh * bf2f((unsigned short)xT[p*72 + t]);
                Yu[(size_t)(b*L_ + c*64 + t)*DINNER_ + xch0 + p] = f2bf(yv);
            }

    // --- S^T = xT · BwT^T ---
    floatx4 accS[2][2];
#pragma unroll
    for (int i = 0; i < 2; i++)
#pragma unroll
        for (int j = 0; j < 2; j++) accS[i][j] = (floatx4){0.f,0.f,0.f,0.f};
#pragma unroll
    for (int kk = 0; kk < 64; kk += 32) {
        short8 af[2], bfv[2];
#pragma unroll
        for (int i = 0; i < 2; i++)
            af[i] = *reinterpret_cast<const short8*>(&xT[(wm + i*16 + ln)*72 + kk + quad*8]);
#pragma unroll
        for (int j = 0; j < 2; j++)
            bfv[j] = *reinterpret_cast<const short8*>(&BwT[(wn + j*16 + ln)*72 + kk + quad*8]);
#pragma unroll
        for (int i = 0; i < 2; i++)
#pragma unroll
            for (int j = 0; j < 2; j++)
                accS[i][j] = __builtin_amdgcn_mfma_f32_16x16x32_bf16(af[i], bfv[j], accS[i][j], 0,0,0);
    }
#pragma unroll
    for (int i = 0; i < 2; i++)
#pragma unroll
        for (int j = 0; j < 2; j++)
#pragma unroll
            for (int r = 0; r < 4; r++) {
                int p = wm + i*16 + quad*4 + r;
                int n = wn + j*16 + ln;
                Sg[(size_t)bid * 4096 + p*64 + n] = accS[i][j][r];
            }
}

// ---------------------------------------------------------------------------
// Pass B: prefix over chunks (unchanged).
// ---------------------------------------------------------------------------
__global__ __launch_bounds__(256) void chunk_state_k(
    float* __restrict__ Sg, const float* __restrict__ Eg)
{
    int g  = blockIdx.x * 1024 + threadIdx.x * 4;
    int bh = g >> 12;
    int b  = bh >> 5, h = bh & 31;
    int e  = g & 4095;
    float4 run = make_float4(0.f, 0.f, 0.f, 0.f);
    for (int c = 0; c < NC_; c++) {
        int bid = (b * 64 + c) * 32 + h;
        size_t idx = (size_t)bid * 4096 + e;
        float4 s = *reinterpret_cast<float4*>(&Sg[idx]);
        float  E = Eg[bid];
        *reinterpret_cast<float4*>(&Sg[idx]) = run;
        run.x = run.x * E + s.x;
        run.y = run.y * E + s.y;
        run.z = run.z * E + s.z;
        run.w = run.w * E + s.w;
    }
}

// ---------------------------------------------------------------------------
// Pass C: Y += e^{cum[t]} * C·hprev^T. C from xc; cums recomputed from dtf.
// ---------------------------------------------------------------------------
__global__ __launch_bounds__(256) void chunk_inter_k(
    const bf16* __restrict__ xc, const float* __restrict__ Sg,
    const float* __restrict__ dtf, const float* __restrict__ A_log,
    bf16* __restrict__ Yg)
{
    __shared__ short Cst[64*72];
    __shared__ short hpT[64*72];
    __shared__ float dts[64], cums[64], wcumL[64];

    const int tid = threadIdx.x;
    const int bid = blockIdx.x;
    const int h   = bid & 31;
    const int bc  = bid >> 5;
    const int c   = bc & 63;
    const int b   = bc >> 6;
    const unsigned short* xcu = (const unsigned short*)xc;

    const float Ah = -__expf(A_log[h]);

    for (int q = tid; q < 512; q += 256) {
        int r = q >> 3, c8 = (q & 7) * 8;
        *reinterpret_cast<uint4*>(&Cst[r*72 + c8]) =
            *reinterpret_cast<const uint4*>(xcu + (size_t)(b*L_ + c*64 + r)*CONVDIM_ + 2112 + c8);
    }
    for (int q = tid; q < 1024; q += 256) {
        int p = q >> 4, n4 = (q & 15) * 4;
        float4 v = *reinterpret_cast<const float4*>(&Sg[(size_t)bid * 4096 + p*64 + n4]);
        unsigned int lo = (unsigned int)f2bf(v.x) | ((unsigned int)f2bf(v.y) << 16);
        unsigned int hi = (unsigned int)f2bf(v.z) | ((unsigned int)f2bf(v.w) << 16);
        *reinterpret_cast<uint2*>(&hpT[p*72 + n4]) = make_uint2(lo, hi);
    }
    if (tid < 64) dts[tid] = dtf[(size_t)(b*L_ + c*64 + tid) * NH_ + h];
    __syncthreads();
    if (tid == 0) {
        float cc = 0.f;
        for (int t = 0; t < 64; t++) { cc += dts[t] * Ah; cums[t] = cc; }
    }
    __syncthreads();
    if (tid < 64) wcumL[tid] = __expf(cums[tid]);
    __syncthreads();

    const int wave = tid >> 6, lane = tid & 63;
    const int ln = lane & 15, quad = lane >> 4;
    const int wm = (wave >> 1) * 32, wn = (wave & 1) * 32;

    floatx4 acc[2][2];
#pragma unroll
    for (int i = 0; i < 2; i++)
#pragma unroll
        for (int j = 0; j < 2; j++) acc[i][j] = (floatx4){0.f,0.f,0.f,0.f};
#pragma unroll
    for (int kk = 0; kk < 64; kk += 32) {
        short8 af[2], bfv[2];
#pragma unroll
        for (int i = 0; i < 2; i++)
            af[i] = *reinterpret_cast<const short8*>(&Cst[(wm + i*16 + ln)*72 + kk + quad*8]);
#pragma unroll
        for (int j = 0; j < 2; j++)
            bfv[j] = *reinterpret_cast<const short8*>(&hpT[(wn + j*16 + ln)*72 + kk + quad*8]);
#pragma unroll
        for (int i = 0; i < 2; i++)
#pragma unroll
            for (int j = 0; j < 2; j++)
                acc[i][j] = __builtin_amdgcn_mfma_f32_16x16x32_bf16(af[i], bfv[j], acc[i][j], 0,0,0);
    }
    unsigned short* Yu = (unsigned short*)Yg;
#pragma unroll
    for (int i = 0; i < 2; i++)
#pragma unroll
        for (int j = 0; j < 2; j++)
#pragma unroll
            for (int r = 0; r < 4; r++) {
                int t = wm + i*16 + quad*4 + r;
                int p = wn + j*16 + ln;
                size_t idx = (size_t)(b*L_ + c*64 + t)*DINNER_ + h*64 + p;
                float yv = bf2f(Yu[idx]) + wcumL[t] * acc[i][j][r];
                Yu[idx] = f2bf(yv);
            }
}

// ---------------------------------------------------------------------------
// gate + RMSNorm (unchanged).
// ---------------------------------------------------------------------------
__global__ __launch_bounds__(256) void gate_norm_k(
    bf16* __restrict__ y, const bf16* __restrict__ zbuf, const float* __restrict__ nw)
{
    __shared__ float red[4];
    int row = blockIdx.x;
    int tid = threadIdx.x;
    unsigned short* yy = (unsigned short*)y;
    const unsigned short* zz = (const unsigned short*)zbuf;

    uint4 yv = *reinterpret_cast<uint4*>(&yy[(size_t)row * DINNER_ + tid * 8]);
    uint4 zv = *reinterpret_cast<const uint4*>(&zz[(size_t)row * DINNER_ + tid * 8]);
    unsigned int yw[4] = {yv.x, yv.y, yv.z, yv.w};
    unsigned int zw[4] = {zv.x, zv.y, zv.z, zv.w};
    float g[8];
    float ss = 0.f;
#pragma unroll
    for (int q = 0; q < 4; q++) {
        float y0 = bf2f((unsigned short)(yw[q] & 0xffffu)), y1 = bf2f((unsigned short)(yw[q] >> 16));
        float z0 = bf2f((unsigned short)(zw[q] & 0xffffu)), z1 = bf2f((unsigned short)(zw[q] >> 16));
        float g0 = y0 * (z0 / (1.f + __expf(-z0)));
        float g1 = y1 * (z1 / (1.f + __expf(-z1)));
        g[q * 2] = g0; g[q * 2 + 1] = g1;
        ss += g0 * g0 + g1 * g1;
    }
#pragma unroll
    for (int o = 1; o < 64; o <<= 1) ss += __shfl_xor(ss, o);
    if ((tid & 63) == 0) red[tid >> 6] = ss;
    __syncthreads();
    float tot = red[0] + red[1] + red[2] + red[3];
    float rinv = rsqrtf(tot * (1.f / DINNER_) + 1e-5f);

    unsigned int ow[4];
#pragma unroll
    for (int q = 0; q < 4; q++) {
        float w0 = nw[tid * 8 + q * 2];
        float w1 = nw[tid * 8 + q * 2 + 1];
        unsigned short o0 = f2bf(g[q * 2] * rinv * w0);
        unsigned short o1 = f2bf(g[q * 2 + 1] * rinv * w1);
        ow[q] = (unsigned int)o0 | ((unsigned int)o1 << 16);
    }
    *reinterpret_cast<uint4*>(&yy[(size_t)row * DINNER_ + tid * 8]) =
        make_uint4(ow[0], ow[1], ow[2], ow[3]);
}

// ---------------------------------------------------------------------------

extern "C" void kernel_launch(void* const* d_in, const int* in_sizes, int n_in,
                              void* d_out, int out_size, void* d_ws, size_t ws_size,
                              hipStream_t stream)
{
    const float* X    = (const float*)d_in[0];
    const float* Wip  = (const float*)d_in[1];
    const float* cw   = (const float*)d_in[2];
    const float* cb   = (const float*)d_in[3];
    const float* dtb  = (const float*)d_in[4];
    const float* Alog = (const float*)d_in[5];
    const float* Dp   = (const float*)d_in[6];
    const float* nw   = (const float*)d_in[7];
    const float* Wop  = (const float*)d_in[8];
    const float* Wth  = (const float*)d_in[9];
    float* out = (float*)d_out;

    // ws layout (peak 106,446,848 B — same proven ceiling as rounds 7/8):
    //   [0, 33554432)          zbuf (gemm1->gate); Wopb/Wthb alias after gate
    //   [33554432, 69730304)   xr (gemm1->conv_all+dt_k); then Yg
    //                          [33554432, 67108864) (chunk_intra->gemm2)
    //   [69730304, 105381888)  xc M x 2176 bf16 (conv_all->chunk_inter);
    //                          Xb/Wipb alias pre-gemm1; Hbuf aliases gemm2->gemm3
    //   [105381888, 106430464) dtf M x 32 f32 (dt_k->chunk_inter)
    //   [106430464, 106446848) Eg 4096 f32
    // Sg lives in d_out (dead before gemm3 overwrites d_out).
    char* ws = (char*)d_ws;
    bf16*  zbuf = (bf16*) (ws);
    bf16*  Wopb = (bf16*) (ws);
    bf16*  Wthb = (bf16*) (ws + 4194304);
    bf16*  xr   = (bf16*) (ws + 33554432);
    bf16*  Yg   = (bf16*) (ws + 33554432);
    bf16*  xc   = (bf16*) (ws + 69730304);
    bf16*  Xb   = (bf16*) (ws + 69730304);
    bf16*  Wipb = (bf16*) (ws + 69730304 + 16777216);
    bf16*  Hbuf = (bf16*) (ws + 69730304);
    float* dtf  = (float*)(ws + 105381888);
    float* Eg   = (float*)(ws + 106430464);
    float* Sg   = (float*)d_out;

    dim3 blk(256);

    // 0) casts (Wipb padded to 4352 rows; pad cols never stored)
    cast_f32_bf16_k<<<(M_ * DIM_) / 2048, blk, 0, stream>>>(X, Xb);
    cast_f32_bf16_k<<<(DIP_ * DIM_) / 2048, blk, 0, stream>>>(Wip, Wipb);

    // 1) zxbcdt = Xb @ Wipb^T; split: z -> zbuf, xBC+dt_raw -> xr
    gemm_bt16<bf16><<<dim3(34, M_ / 128), blk, 0, stream>>>(
        Xb, Wipb, zbuf, xr, M_, DIP_, DIM_, DINNER_, DINNER_, XRW_);

    // 2) conv+silu (all channels, once) and softplus(dt)
    dt_k<<<(M_ * NH_) / 256, blk, 0, stream>>>(xr, dtb, dtf);
    conv_all_k<<<(M_ * 272) / 256, blk, 0, stream>>>(xr, cw, cb, xc);

    // 3) chunked scan (Yg overwrites xr: dead after conv)
    chunk_intra_k<<<B_ * NC_ * NH_, blk, 0, stream>>>(
        xc, dtf, Alog, Dp, Yg, Sg, Eg);
    chunk_state_k<<<256, blk, 0, stream>>>(Sg, Eg);
    chunk_inter_k<<<B_ * NC_ * NH_, blk, 0, stream>>>(xc, Sg, dtf, Alog, Yg);

    // 4) gate + RMSNorm in place on Yg (last read of zbuf)
    gate_norm_k<<<M_, blk, 0, stream>>>(Yg, zbuf, nw);

    // 4b) cast out_proj / to_h weights into dead zbuf region
    cast_f32_bf16_k<<<(DIM_ * DINNER_) / 2048, blk, 0, stream>>>(Wop, Wopb);
    cast_f32_bf16_k<<<(DINNER_ * DIM_) / 2048, blk, 0, stream>>>(Wth, Wthb);

    // 5) H = ynorm @ out_proj^T -> Hbuf (xc dead after chunk_inter)
    gemm_bt16<bf16><<<dim3(DIM_ / 128, M_ / 128), blk, 0, stream>>>(
        Yg, Wopb, Hbuf, Hbuf, M_, DIM_, DINNER_, DIM_, DIM_, DIM_);

    // 6) HKV = H @ to_h^T; f32 split HK | HV into d_out (Sg dead)
    gemm_bt16<float><<<dim3(DINNER_ / 128, M_ / 128), blk, 0, stream>>>(
        Hbuf, Wthb, out, out + (size_t)M_ * DIM_, M_, DINNER_, DIM_, DIM_, DIM_, DIM_);
}